// Round 10
// baseline (83.681 us; speedup 1.0000x reference)
//
#include <hip/hip_runtime.h>

// ---------------------------------------------------------------------------
// FeatureNet: kNN(K=8) relative grouping -> [conv1x1+BN+ReLU] x3 -> max over K
// B=8, N=2048, DIM=128, fp32 in/out.
//
// prep : fold BN; W1/W2 as 4 bf16 planes in MFMA FRAGMENT ORDER; C0/C1/C2; W0F
// knn  : R10: 1024 blocks x 512 thr (16 q x 32 lanes). Candidates staged in
//        TWO 1024-halves (16.9KB LDS -> 4 blocks/CU, 32 waves/CU) as split
//        float2 planes (xy / z,sq; pad per 32 -> 2-way-free b64 reads).
//        Keys-only dual-chain top-8 -> 5 shfl_xor merge rounds -> exact
//        threshold -> hitmask rescan + popc/scan -> idx[q][8] + y rows.
// fused: PERSISTENT: 256 blocks (1/CU), 8 chunks each, W in 128 VGPRs.
//        A double-buffered LDS, H own region, OS written coalesced at end.
//        XCD-aligned: block bid -> batch bid&7 (1MB y slice per XCD L2).
// ---------------------------------------------------------------------------

#define EPSF 1e-5f
#define FMAXV 3.402823466e+38f

#define NB 8
#define NN 2048
#define KNBR 8
#define DIMF 128
#define NQ (NB * NN)        // 16384
#define NPAIR (NQ * KNBR)   // 131072

// ws layout. W planes in u16 units [0, 65536) == floats [0, 32768).
#define OFF16_W1H 0          // 16384 u16 (fragment order)
#define OFF16_W1L 16384
#define OFF16_W2H 32768
#define OFF16_W2L 49152
#define OFF_C0 32768         // float units
#define OFF_C1 32896
#define OFF_C2 33024
#define OFF_W0F 33152        // 384
#define OFF_Y 33792          // 2097152 floats
#define OFF_IDX (OFF_Y + NQ * DIMF)   // 131072 ints

typedef __attribute__((ext_vector_type(4))) float f32x4;
typedef __attribute__((ext_vector_type(8))) short short8v;

__device__ __forceinline__ float relu_f(float a) { return fmaxf(a, 0.0f); }

// fp32 -> bf16(hi, RNE) + bf16(lo, trunc of residual)
__device__ __forceinline__ void split3(float f, unsigned& hi, unsigned& lo) {
  const unsigned u = __float_as_uint(f);
  const unsigned h = (u + 0x7FFFu + ((u >> 16) & 1u)) >> 16;
  const float hf = __uint_as_float(h << 16);
  lo = __float_as_uint(f - hf) >> 16;
  hi = h;
}

__device__ __forceinline__ f32x4 mfma16x16x32bf(short8v a, short8v b, f32x4 c) {
  return __builtin_amdgcn_mfma_f32_16x16x32_bf16(a, b, c, 0, 0, 0);
}

// ---- named-scalar selection primitives (R7 lesson: NO array state) ----
#define KINS8(K0, K1, K2, K3, K4, K5, K6, K7, dv)     \
  {                                                   \
    float t_ = (dv), n_;                              \
    n_ = fminf(K0, t_); t_ = fmaxf(K0, t_); K0 = n_;  \
    n_ = fminf(K1, t_); t_ = fmaxf(K1, t_); K1 = n_;  \
    n_ = fminf(K2, t_); t_ = fmaxf(K2, t_); K2 = n_;  \
    n_ = fminf(K3, t_); t_ = fmaxf(K3, t_); K3 = n_;  \
    n_ = fminf(K4, t_); t_ = fmaxf(K4, t_); K4 = n_;  \
    n_ = fminf(K5, t_); t_ = fmaxf(K5, t_); K5 = n_;  \
    n_ = fminf(K6, t_); t_ = fmaxf(K6, t_); K6 = n_;  \
    n_ = fminf(K7, t_); t_ = fmaxf(K7, t_); K7 = n_;  \
  }

#define KCSWAP(a, b)                  \
  {                                   \
    const float mn_ = fminf(a, b);    \
    const float mx_ = fmaxf(a, b);    \
    (a) = mn_; (b) = mx_;             \
  }

#define KCLEAN8()                                               \
  KCSWAP(k0, k4) KCSWAP(k1, k5) KCSWAP(k2, k6) KCSWAP(k3, k7)   \
  KCSWAP(k0, k2) KCSWAP(k1, k3) KCSWAP(k4, k6) KCSWAP(k5, k7)   \
  KCSWAP(k0, k1) KCSWAP(k2, k3) KCSWAP(k4, k5) KCSWAP(k6, k7)

#define KMERGE(mv)                                              \
  {                                                             \
    const float q0_ = __shfl_xor(k0, mv, 64);                   \
    const float q1_ = __shfl_xor(k1, mv, 64);                   \
    const float q2_ = __shfl_xor(k2, mv, 64);                   \
    const float q3_ = __shfl_xor(k3, mv, 64);                   \
    const float q4_ = __shfl_xor(k4, mv, 64);                   \
    const float q5_ = __shfl_xor(k5, mv, 64);                   \
    const float q6_ = __shfl_xor(k6, mv, 64);                   \
    const float q7_ = __shfl_xor(k7, mv, 64);                   \
    k0 = fminf(k0, q7_); k1 = fminf(k1, q6_);                   \
    k2 = fminf(k2, q5_); k3 = fminf(k3, q4_);                   \
    k4 = fminf(k4, q3_); k5 = fminf(k5, q2_);                   \
    k6 = fminf(k6, q1_); k7 = fminf(k7, q0_);                   \
    KCLEAN8()                                                   \
  }

// ------------------------------- prep --------------------------------------
__global__ __launch_bounds__(256) void prep_kernel(
    const float* __restrict__ w0, const float* __restrict__ b0,
    const float* __restrict__ wstk, const float* __restrict__ bstk,
    const float* __restrict__ g, const float* __restrict__ be,
    const float* __restrict__ bm, const float* __restrict__ bv,
    float* __restrict__ ws) {
  const int i = blockIdx.x * 256 + threadIdx.x;  // 16384
  unsigned short* __restrict__ wsh = (unsigned short*)ws;
  {
    const int fo = i >> 7, k = i & 127;
    const float s1 = g[128 + fo] / sqrtf(bv[128 + fo] + EPSF);
    const float s2 = g[256 + fo] / sqrtf(bv[256 + fo] + EPSF);
    unsigned h1, l1, h2, l2;
    split3(wstk[i] * s1, h1, l1);
    split3(wstk[16384 + i] * s2, h2, l2);
    const int dst = ((fo >> 4) * 4 + (k >> 5)) * 512 +
                    (((k >> 3) & 3) * 16 + (fo & 15)) * 8 + (k & 7);
    wsh[OFF16_W1H + dst] = (unsigned short)h1;
    wsh[OFF16_W1L + dst] = (unsigned short)l1;
    wsh[OFF16_W2H + dst] = (unsigned short)h2;
    wsh[OFF16_W2L + dst] = (unsigned short)l2;
  }
  if (blockIdx.x == 0 && threadIdx.x < 128) {
    const int fo = threadIdx.x;
    const float s0 = g[fo] / sqrtf(bv[fo] + EPSF);
    const float s1 = g[128 + fo] / sqrtf(bv[128 + fo] + EPSF);
    const float s2 = g[256 + fo] / sqrtf(bv[256 + fo] + EPSF);
    ws[OFF_C0 + fo] = (b0[fo] - bm[fo]) * s0 + be[fo];
    ws[OFF_C1 + fo] = (bstk[fo] - bm[128 + fo]) * s1 + be[128 + fo];
    ws[OFF_C2 + fo] = (bstk[128 + fo] - bm[256 + fo]) * s2 + be[256 + fo];
    ws[OFF_W0F + 3 * fo + 0] = w0[3 * fo + 0] * s0;
    ws[OFF_W0F + 3 * fo + 1] = w0[3 * fo + 1] * s0;
    ws[OFF_W0F + 3 * fo + 2] = w0[3 * fo + 2] * s0;
  }
}

// ------------------------------- knn (+y) ----------------------------------
// 1024 blocks x 512 thr. bb = bid>>7, queries qloc0..+16. 32 lanes/query
// (sg=t&31), slice = 64 cands (32 per half). Halves staged into split planes:
// xyp/zsp float2[1056], idx = i + (i>>5) pad -> lane base sg*33 (2-way free).
__global__ __launch_bounds__(512, 8) void knn_kernel(const float* __restrict__ x,
                                                     float* __restrict__ ws) {
  __shared__ float2 xyp[1056];
  __shared__ float2 zsp[1056];
  const int t = threadIdx.x;
  const int bid = blockIdx.x;           // 1024
  const int bb = bid >> 7;
  const int qloc0 = (bid & 127) * 16;
  const float* __restrict__ xb = x + bb * 3 * NN;

  const int qi = t >> 5;                // 0..15
  const int sg = t & 31;                // slice
  const int n = qloc0 + qi;
  const int q = bb * NN + n;
  const float qx0 = xb[n], qx1 = xb[2048 + n], qx2 = xb[4096 + n];
  const float sqn = fmaf(qx2, qx2, fmaf(qx1, qx1, qx0 * qx0));

  // ---- y row: lane sg writes features [sg*4, sg*4+4) of query q ----
  {
    const float* __restrict__ W0f = ws + OFF_W0F + sg * 12;
    float* __restrict__ yo = ws + OFF_Y + (long)q * 128 + sg * 4;
    float4 yv;
    yv.x = fmaf(W0f[2], qx2, fmaf(W0f[1], qx1, W0f[0] * qx0));
    yv.y = fmaf(W0f[5], qx2, fmaf(W0f[4], qx1, W0f[3] * qx0));
    yv.z = fmaf(W0f[8], qx2, fmaf(W0f[7], qx1, W0f[6] * qx0));
    yv.w = fmaf(W0f[11], qx2, fmaf(W0f[10], qx1, W0f[9] * qx0));
    *(float4*)yo = yv;
  }

#define STAGE_HALF(h)                                           \
  {                                                             \
    _Pragma("unroll") for (int k2 = 0; k2 < 2; ++k2) {          \
      const int i_ = t + k2 * 512;                              \
      const int c_ = (h) * 1024 + i_;                           \
      const float a0_ = xb[c_];                                 \
      const float a1_ = xb[2048 + c_];                          \
      const float a2_ = xb[4096 + c_];                          \
      const float sq_ = fmaf(a2_, a2_, fmaf(a1_, a1_, a0_ * a0_)); \
      const int ii_ = i_ + (i_ >> 5);                           \
      xyp[ii_] = make_float2(a0_, a1_);                         \
      zsp[ii_] = make_float2(a2_, sq_);                         \
    }                                                           \
  }

  const float2* __restrict__ xr = xyp + sg * 33;
  const float2* __restrict__ zr = zsp + sg * 33;

  float e0 = FMAXV, e1 = FMAXV, e2 = FMAXV, e3 = FMAXV,
        e4 = FMAXV, e5 = FMAXV, e6 = FMAXV, e7 = FMAXV;
  float o0 = FMAXV, o1 = FMAXV, o2 = FMAXV, o3 = FMAXV,
        o4 = FMAXV, o5 = FMAXV, o6 = FMAXV, o7 = FMAXV;

#define P1_HALF()                                                         \
  _Pragma("unroll 2") for (int mm = 0; mm < 32; mm += 2) {                \
    const float2 exy = xr[mm], ezs = zr[mm];                              \
    const float2 oxy = xr[mm + 1], ozs = zr[mm + 1];                      \
    const float innerE = fmaf(qx2, ezs.x, fmaf(qx1, exy.y, qx0 * exy.x)); \
    const float innerO = fmaf(qx2, ozs.x, fmaf(qx1, oxy.y, qx0 * oxy.x)); \
    const float dE = (sqn - 2.0f * innerE) + ezs.y;                       \
    const float dO = (sqn - 2.0f * innerO) + ozs.y;                       \
    KINS8(e0, e1, e2, e3, e4, e5, e6, e7, dE)                             \
    KINS8(o0, o1, o2, o3, o4, o5, o6, o7, dO)                             \
  }

  STAGE_HALF(0)
  __syncthreads();
  P1_HALF()
  __syncthreads();
  STAGE_HALF(1)
  __syncthreads();
  P1_HALF()

  // low-8 of the two chains (bitonic) -> cleanup -> sorted k0..k7
  float k0 = fminf(e0, o7), k1 = fminf(e1, o6);
  float k2 = fminf(e2, o5), k3 = fminf(e3, o4);
  float k4 = fminf(e4, o3), k5 = fminf(e5, o2);
  float k6 = fminf(e6, o1), k7 = fminf(e7, o0);
  KCLEAN8()
  // 32 lanes -> global top-8 keys (all lanes converge)
  KMERGE(1) KMERGE(2) KMERGE(4) KMERGE(8) KMERGE(16)
  const float thr = k7;  // exact global 8th-smallest distance

  // ---- phase 2: hitmask rescan (bit-identical d expression) ----
  unsigned am = 0, bm2 = 0;
  __syncthreads();
  STAGE_HALF(0)
  __syncthreads();
#pragma unroll
  for (int mm = 0; mm < 32; ++mm) {
    const float2 cxy = xr[mm];
    const float2 czs = zr[mm];
    const float inner = fmaf(qx2, czs.x, fmaf(qx1, cxy.y, qx0 * cxy.x));
    const float d = (sqn - 2.0f * inner) + czs.y;
    am |= (d <= thr) ? (1u << mm) : 0u;
  }
  __syncthreads();
  STAGE_HALF(1)
  __syncthreads();
#pragma unroll
  for (int mm = 0; mm < 32; ++mm) {
    const float2 cxy = xr[mm];
    const float2 czs = zr[mm];
    const float inner = fmaf(qx2, czs.x, fmaf(qx1, cxy.y, qx0 * cxy.x));
    const float d = (sqn - 2.0f * inner) + czs.y;
    bm2 |= (d <= thr) ? (1u << mm) : 0u;
  }

  // ---- counts + exclusive scans over the 32-lane group ----
  const int cA = __popc(am), cB = __popc(bm2);
  int incA = cA, incB = cB, tq;
  tq = __shfl_up(incA, 1, 32); incA += (sg >= 1) ? tq : 0;
  tq = __shfl_up(incA, 2, 32); incA += (sg >= 2) ? tq : 0;
  tq = __shfl_up(incA, 4, 32); incA += (sg >= 4) ? tq : 0;
  tq = __shfl_up(incA, 8, 32); incA += (sg >= 8) ? tq : 0;
  tq = __shfl_up(incA, 16, 32); incA += (sg >= 16) ? tq : 0;
  tq = __shfl_up(incB, 1, 32); incB += (sg >= 1) ? tq : 0;
  tq = __shfl_up(incB, 2, 32); incB += (sg >= 2) ? tq : 0;
  tq = __shfl_up(incB, 4, 32); incB += (sg >= 4) ? tq : 0;
  tq = __shfl_up(incB, 8, 32); incB += (sg >= 8) ? tq : 0;
  tq = __shfl_up(incB, 16, 32); incB += (sg >= 16) ? tq : 0;
  const int totA = __shfl(incA, 31, 32);
  const int offA = incA - cA;
  const int offB = totA + incB - cB;

  // ---- extraction: first 8 hits in ascending candidate-index order ----
  int* __restrict__ idxg = (int*)(ws + OFF_IDX);
  {
    int pos = offA;
    unsigned w = am;
    while (w) {
      const int b = __ffs(w) - 1;
      w &= w - 1;
      if (pos < 8) idxg[q * 8 + pos] = bb * NN + sg * 32 + b;
      ++pos;
    }
    pos = offB;
    w = bm2;
    while (w) {
      const int b = __ffs(w) - 1;
      w &= w - 1;
      if (pos < 8) idxg[q * 8 + pos] = bb * NN + 1024 + sg * 32 + b;
      ++pos;
    }
  }
#undef STAGE_HALF
#undef P1_HALF
}

// --------------------------- persistent fused ------------------------------
// 256 blocks x 512 thr (8 waves: wr=w>>2 pair-half, wc=w&3 fo-slice).
// Block bid: batch bb=bid&7, queries qseg*64..+64 (qseg=bid>>3), 8 chunks of
// 64 pairs. LDS 128KB: A dbuf 2x32KB @0, H 32KB @64K, OS 32KB @96K.
// A-plane 16B chunks swizzled col = kc ^ (row&7); H 16B chunks cc ^= (p&7).
__global__ __launch_bounds__(512, 2) void fused_kernel(float* __restrict__ ws,
                                                       float* __restrict__ out) {
  extern __shared__ char smem[];
  unsigned* __restrict__ H = (unsigned*)(smem + 65536);
  float* __restrict__ OS = (float*)(smem + 98304);

  const float* __restrict__ y = ws + OFF_Y;
  const int* __restrict__ idxg = (const int*)(ws + OFF_IDX);
  const unsigned short* __restrict__ wsu = (const unsigned short*)ws;

  const int t = threadIdx.x;
  const int lane = t & 63, w = t >> 6;
  const int wr = w >> 2, wc = w & 3;
  const int bid = blockIdx.x;
  const int bb = bid & 7, qseg = bid >> 3;
  const int chunk0 = bb * 256 + qseg * 8;

  // ---- W fragments -> registers (once; coalesced 1KB/wave frag loads) ----
  short8v w1h[2][4], w1l[2][4], w2h[2][4], w2l[2][4];
#pragma unroll
  for (int ft = 0; ft < 2; ++ft)
#pragma unroll
    for (int ks = 0; ks < 4; ++ks) {
      const int off = ((wc * 2 + ft) * 4 + ks) * 512 + lane * 8;
      w1h[ft][ks] = *(const short8v*)(wsu + OFF16_W1H + off);
      w1l[ft][ks] = *(const short8v*)(wsu + OFF16_W1L + off);
      w2h[ft][ks] = *(const short8v*)(wsu + OFF16_W2H + off);
      w2l[ft][ks] = *(const short8v*)(wsu + OFF16_W2L + off);
    }

  const float c1v0 = (ws + OFF_C1)[wc * 32 + (lane & 15)];
  const float c1v1 = (ws + OFF_C1)[wc * 32 + 16 + (lane & 15)];
  const float c2v0 = (ws + OFF_C2)[wc * 32 + (lane & 15)];
  const float c2v1 = (ws + OFF_C2)[wc * 32 + 16 + (lane & 15)];

  // ---- per-thread A-staging constants ----
  const int row = t >> 3, part8 = t & 7;
  const float* __restrict__ c0p = ws + OFF_C0 + part8 * 16;
  const float4 c0a = *(const float4*)(c0p + 0);
  const float4 c0b = *(const float4*)(c0p + 4);
  const float4 c0c = *(const float4*)(c0p + 8);
  const float4 c0d = *(const float4*)(c0p + 12);

// pack 8 floats (relu'd h1 values) into hi/lo int4 and write swizzled
#define PACK_WRITE_A(base, hv, kc)                              \
  {                                                             \
    unsigned hh[8], ll[8];                                      \
    _Pragma("unroll") for (int e = 0; e < 8; ++e)               \
        split3(hv[e], hh[e], ll[e]);                            \
    int4 hp, lp;                                                \
    hp.x = (int)(hh[0] | (hh[1] << 16));                        \
    hp.y = (int)(hh[2] | (hh[3] << 16));                        \
    hp.z = (int)(hh[4] | (hh[5] << 16));                        \
    hp.w = (int)(hh[6] | (hh[7] << 16));                        \
    lp.x = (int)(ll[0] | (ll[1] << 16));                        \
    lp.y = (int)(ll[2] | (ll[3] << 16));                        \
    lp.z = (int)(ll[4] | (ll[5] << 16));                        \
    lp.w = (int)(ll[6] | (ll[7] << 16));                        \
    const int col = (kc) ^ (row & 7);                           \
    *(int4*)((base) + row * 256 + col * 16) = hp;               \
    *(int4*)((base) + 16384 + row * 256 + col * 16) = lp;       \
  }

  // ---- prologue: stage A[0] into buf0 ----
  {
    const int gp = chunk0 * 64 + row;
    const int mg = idxg[gp];
    const float* __restrict__ ym = y + (long)mg * 128 + part8 * 16;
    const float* __restrict__ yn = y + (long)(gp >> 3) * 128 + part8 * 16;
    const float4 a0 = *(const float4*)(ym + 0);
    const float4 a1 = *(const float4*)(ym + 4);
    const float4 a2 = *(const float4*)(ym + 8);
    const float4 a3 = *(const float4*)(ym + 12);
    const float4 n0 = *(const float4*)(yn + 0);
    const float4 n1 = *(const float4*)(yn + 4);
    const float4 n2 = *(const float4*)(yn + 8);
    const float4 n3 = *(const float4*)(yn + 12);
    float hv0[8] = {relu_f(a0.x - n0.x + c0a.x), relu_f(a0.y - n0.y + c0a.y),
                    relu_f(a0.z - n0.z + c0a.z), relu_f(a0.w - n0.w + c0a.w),
                    relu_f(a1.x - n1.x + c0b.x), relu_f(a1.y - n1.y + c0b.y),
                    relu_f(a1.z - n1.z + c0b.z), relu_f(a1.w - n1.w + c0b.w)};
    float hv1[8] = {relu_f(a2.x - n2.x + c0c.x), relu_f(a2.y - n2.y + c0c.y),
                    relu_f(a2.z - n2.z + c0c.z), relu_f(a2.w - n2.w + c0c.w),
                    relu_f(a3.x - n3.x + c0d.x), relu_f(a3.y - n3.y + c0d.y),
                    relu_f(a3.z - n3.z + c0d.z), relu_f(a3.w - n3.w + c0d.w)};
    PACK_WRITE_A(smem, hv0, part8 * 2)
    PACK_WRITE_A(smem, hv1, part8 * 2 + 1)
  }
  __syncthreads();

#pragma unroll 1
  for (int j = 0; j < 8; ++j) {
    char* __restrict__ Acur = smem + (j & 1) * 32768;
    char* __restrict__ Anxt = smem + ((j & 1) ^ 1) * 32768;

    int mg_next = 0, gp_next = 0;
    if (j < 7) {
      gp_next = (chunk0 + j + 1) * 64 + row;
      mg_next = idxg[gp_next];
    }

    // ---- g1: acc = h1 . W1^T (bf16x3), A from Acur ----
    f32x4 acc[2][2];
#pragma unroll
    for (int pt = 0; pt < 2; ++pt)
#pragma unroll
      for (int ft = 0; ft < 2; ++ft) acc[pt][ft] = (f32x4){0.f, 0.f, 0.f, 0.f};
#pragma unroll
    for (int ks = 0; ks < 4; ++ks) {
      const int kc = ks * 4 + (lane >> 4);
#pragma unroll
      for (int pt = 0; pt < 2; ++pt) {
        const int arow = wr * 32 + pt * 16 + (lane & 15);
        const int col = kc ^ (arow & 7);
        const short8v ah = *(const short8v*)(Acur + arow * 256 + col * 16);
        const short8v al =
            *(const short8v*)(Acur + 16384 + arow * 256 + col * 16);
#pragma unroll
        for (int ft = 0; ft < 2; ++ft) {
          acc[pt][ft] = mfma16x16x32bf(al, w1h[ft][ks], acc[pt][ft]);
          acc[pt][ft] = mfma16x16x32bf(ah, w1l[ft][ks], acc[pt][ft]);
          acc[pt][ft] = mfma16x16x32bf(ah, w1h[ft][ks], acc[pt][ft]);
        }
      }
    }

    // ---- issue next chunk's y loads (latency hides under H + g2) ----
    float4 a0, a1, a2, a3, n0, n1, n2, n3;
    if (j < 7) {
      const float* __restrict__ ym = y + (long)mg_next * 128 + part8 * 16;
      const float* __restrict__ yn = y + (long)(gp_next >> 3) * 128 + part8 * 16;
      a0 = *(const float4*)(ym + 0);
      a1 = *(const float4*)(ym + 4);
      a2 = *(const float4*)(ym + 8);
      a3 = *(const float4*)(ym + 12);
      n0 = *(const float4*)(yn + 0);
      n1 = *(const float4*)(yn + 4);
      n2 = *(const float4*)(yn + 8);
      n3 = *(const float4*)(yn + 12);
    }

    // ---- g1 epilogue: relu(acc+c1) -> H (packed u32, swizzled) ----
#pragma unroll
    for (int pt = 0; pt < 2; ++pt)
#pragma unroll
      for (int ft = 0; ft < 2; ++ft) {
        const int fo = wc * 32 + ft * 16 + (lane & 15);
        const int cc = fo >> 2;
        const float cb = ft ? c1v1 : c1v0;
#pragma unroll
        for (int reg = 0; reg < 4; ++reg) {
          const int p = wr * 32 + pt * 16 + (lane >> 4) * 4 + reg;
          const float vv = relu_f(acc[pt][ft][reg] + cb);
          unsigned hh, ll;
          split3(vv, hh, ll);
          H[p * 128 + ((cc ^ (p & 7)) << 2) + (fo & 3)] = (hh << 16) | ll;
        }
      }
    __syncthreads();  // H ready

    // ---- g2: acc2 = h2 . W2^T (bf16x3), A from H ----
    f32x4 acc2[2][2];
#pragma unroll
    for (int pt = 0; pt < 2; ++pt)
#pragma unroll
      for (int ft = 0; ft < 2; ++ft) acc2[pt][ft] = (f32x4){0.f, 0.f, 0.f, 0.f};
#pragma unroll
    for (int ks = 0; ks < 4; ++ks) {
      const int cc0 = ks * 8 + (lane >> 4) * 2;
#pragma unroll
      for (int pt = 0; pt < 2; ++pt) {
        const int p = wr * 32 + pt * 16 + (lane & 15);
        const int4 u0 = *(const int4*)&H[p * 128 + ((cc0 ^ (p & 7)) << 2)];
        const int4 u1 = *(const int4*)&H[p * 128 + (((cc0 + 1) ^ (p & 7)) << 2)];
        const unsigned uu[8] = {(unsigned)u0.x, (unsigned)u0.y, (unsigned)u0.z,
                                (unsigned)u0.w, (unsigned)u1.x, (unsigned)u1.y,
                                (unsigned)u1.z, (unsigned)u1.w};
        short8v ah, al;
#pragma unroll
        for (int e = 0; e < 8; ++e) {
          ah[e] = (short)(uu[e] >> 16);
          al[e] = (short)(uu[e] & 0xFFFFu);
        }
#pragma unroll
        for (int ft = 0; ft < 2; ++ft) {
          acc2[pt][ft] = mfma16x16x32bf(al, w2h[ft][ks], acc2[pt][ft]);
          acc2[pt][ft] = mfma16x16x32bf(ah, w2l[ft][ks], acc2[pt][ft]);
          acc2[pt][ft] = mfma16x16x32bf(ah, w2h[ft][ks], acc2[pt][ft]);
        }
      }
    }
    __syncthreads();  // H reads done (next iter may overwrite H)

    // ---- g2 epilogue: relu+max over 8 pairs/query -> OS rows j*8.. ----
    {
      const int g = lane >> 4;
#pragma unroll
      for (int pt = 0; pt < 2; ++pt)
#pragma unroll
        for (int ft = 0; ft < 2; ++ft) {
          const int fo = wc * 32 + ft * 16 + (lane & 15);
          const float cb = ft ? c2v1 : c2v0;
          const float v0 = relu_f(acc2[pt][ft][0] + cb);
          const float v1 = relu_f(acc2[pt][ft][1] + cb);
          const float v2 = relu_f(acc2[pt][ft][2] + cb);
          const float v3 = relu_f(acc2[pt][ft][3] + cb);
          float m = fmaxf(fmaxf(v0, v1), fmaxf(v2, v3));
          m = fmaxf(m, __shfl_xor(m, 16, 64));
          if ((g & 1) == 0) {
            const int qloc = wr * 4 + pt * 2 + (g >> 1);
            OS[(j * 8 + qloc) * 128 + fo] = m;
          }
        }
    }

    // ---- pack & write A[j+1] into Anxt (loads returned during g2) ----
    if (j < 7) {
      float hv0[8] = {relu_f(a0.x - n0.x + c0a.x), relu_f(a0.y - n0.y + c0a.y),
                      relu_f(a0.z - n0.z + c0a.z), relu_f(a0.w - n0.w + c0a.w),
                      relu_f(a1.x - n1.x + c0b.x), relu_f(a1.y - n1.y + c0b.y),
                      relu_f(a1.z - n1.z + c0b.z), relu_f(a1.w - n1.w + c0b.w)};
      float hv1[8] = {relu_f(a2.x - n2.x + c0c.x), relu_f(a2.y - n2.y + c0c.y),
                      relu_f(a2.z - n2.z + c0c.z), relu_f(a2.w - n2.w + c0c.w),
                      relu_f(a3.x - n3.x + c0d.x), relu_f(a3.y - n3.y + c0d.y),
                      relu_f(a3.z - n3.z + c0d.z), relu_f(a3.w - n3.w + c0d.w)};
      PACK_WRITE_A(Anxt, hv0, part8 * 2)
      PACK_WRITE_A(Anxt, hv1, part8 * 2 + 1)
    }
    __syncthreads();  // A[j+1] ready; OS rows settled
  }

  // ---- final coalesced out-write: OS[64][128] -> out[bb][f][qseg*64..] ----
  {
    const int f = t >> 2, seg = t & 3;
    float* __restrict__ op = out + (long)(bb * 128 + f) * 2048 + qseg * 64 + seg * 16;
#pragma unroll
    for (int u = 0; u < 4; ++u) {
      float4 o;
      o.x = OS[(seg * 16 + u * 4 + 0) * 128 + f];
      o.y = OS[(seg * 16 + u * 4 + 1) * 128 + f];
      o.z = OS[(seg * 16 + u * 4 + 2) * 128 + f];
      o.w = OS[(seg * 16 + u * 4 + 3) * 128 + f];
      *(float4*)(op + u * 4) = o;
    }
  }
}

// ------------------------------- launch ------------------------------------
extern "C" void kernel_launch(void* const* d_in, const int* in_sizes, int n_in,
                              void* d_out, int out_size, void* d_ws,
                              size_t ws_size, hipStream_t stream) {
  (void)in_sizes; (void)n_in; (void)out_size; (void)ws_size;
  const float* x = (const float*)d_in[0];
  const float* w0 = (const float*)d_in[1];
  const float* b0 = (const float*)d_in[2];
  const float* wst = (const float*)d_in[3];
  const float* bst = (const float*)d_in[4];
  const float* g = (const float*)d_in[5];
  const float* be = (const float*)d_in[6];
  const float* bm = (const float*)d_in[7];
  const float* bv = (const float*)d_in[8];
  float* out = (float*)d_out;
  float* ws = (float*)d_ws;

  hipFuncSetAttribute((const void*)fused_kernel,
                      hipFuncAttributeMaxDynamicSharedMemorySize, 131072);

  prep_kernel<<<64, 256, 0, stream>>>(w0, b0, wst, bst, g, be, bm, bv, ws);
  knn_kernel<<<1024, 512, 0, stream>>>(x, ws);
  fused_kernel<<<256, 512, 131072, stream>>>(ws, out);
}

// Round 11
// 75.239 us; speedup vs baseline: 1.1122x; 1.1122x over previous
//
#include <hip/hip_runtime.h>

// ---------------------------------------------------------------------------
// FeatureNet: kNN(K=8) relative grouping -> [conv1x1+BN+ReLU] x3 -> max over K
// B=8, N=2048, DIM=128, fp32 in/out.
//
// knn  : R11: 1056 blocks x 512 thr. Blocks 0..1023: 16 queries x 32 lanes;
//        whole batch staged ONCE in split float2 planes (33.3KB, pad i+(i>>6)
//        -> 2-way-free b64). Phase1 = 8-cand Batcher sort-8 + fold into
//        sorted-8 chain (13.75 ops/cand vs 21 for insert-chain). 5 shfl_xor
//        merge rounds -> exact threshold -> recompute-rescan masks -> scan ->
//        idx[q][8]. y computed from RAW w0/g/bv (bit-identical to old prep).
//        Blocks 1024..1055: W1/W2 bf16 plane prep + C0/C1/C2 (used by fused
//        only, which launches after). No separate prep kernel.
// fused: PERSISTENT: 256 blocks (1/CU), 8 chunks each, W in 128 VGPRs.
//        A double-buffered LDS, H own region, OS written coalesced at end.
//        XCD-aligned: block bid -> batch bid&7.
// ---------------------------------------------------------------------------

#define EPSF 1e-5f
#define FMAXV 3.402823466e+38f

#define NB 8
#define NN 2048
#define KNBR 8
#define DIMF 128
#define NQ (NB * NN)        // 16384
#define NPAIR (NQ * KNBR)   // 131072

// ws layout. W planes in u16 units [0, 65536) == floats [0, 32768).
#define OFF16_W1H 0          // 16384 u16 (fragment order)
#define OFF16_W1L 16384
#define OFF16_W2H 32768
#define OFF16_W2L 49152
#define OFF_C0 32768         // float units
#define OFF_C1 32896
#define OFF_C2 33024
#define OFF_Y 33792          // 2097152 floats
#define OFF_IDX (OFF_Y + NQ * DIMF)   // 131072 ints

typedef __attribute__((ext_vector_type(4))) float f32x4;
typedef __attribute__((ext_vector_type(8))) short short8v;

__device__ __forceinline__ float relu_f(float a) { return fmaxf(a, 0.0f); }

// fp32 -> bf16(hi, RNE) + bf16(lo, trunc of residual)
__device__ __forceinline__ void split3(float f, unsigned& hi, unsigned& lo) {
  const unsigned u = __float_as_uint(f);
  const unsigned h = (u + 0x7FFFu + ((u >> 16) & 1u)) >> 16;
  const float hf = __uint_as_float(h << 16);
  lo = __float_as_uint(f - hf) >> 16;
  hi = h;
}

__device__ __forceinline__ f32x4 mfma16x16x32bf(short8v a, short8v b, f32x4 c) {
  return __builtin_amdgcn_mfma_f32_16x16x32_bf16(a, b, c, 0, 0, 0);
}

// ---- named-scalar selection primitives (R7 lesson: NO array state) ----
#define KCSWAP(a, b)                  \
  {                                   \
    const float mn_ = fminf(a, b);    \
    const float mx_ = fmaxf(a, b);    \
    (a) = mn_; (b) = mx_;             \
  }

// Batcher odd-even mergesort of 8 keys (19 comparators), ascending
#define SORT8(d0, d1, d2, d3, d4, d5, d6, d7)                   \
  KCSWAP(d0, d1) KCSWAP(d2, d3) KCSWAP(d4, d5) KCSWAP(d6, d7)   \
  KCSWAP(d0, d2) KCSWAP(d1, d3) KCSWAP(d4, d6) KCSWAP(d5, d7)   \
  KCSWAP(d1, d2) KCSWAP(d5, d6)                                 \
  KCSWAP(d0, d4) KCSWAP(d1, d5) KCSWAP(d2, d6) KCSWAP(d3, d7)   \
  KCSWAP(d2, d4) KCSWAP(d3, d5)                                 \
  KCSWAP(d1, d2) KCSWAP(d3, d4) KCSWAP(d5, d6)

// 3-stage bitonic cleanup of a bitonic 8-seq in k0..k7 (sorts ascending)
#define KCLEAN8()                                               \
  KCSWAP(k0, k4) KCSWAP(k1, k5) KCSWAP(k2, k6) KCSWAP(k3, k7)   \
  KCSWAP(k0, k2) KCSWAP(k1, k3) KCSWAP(k4, k6) KCSWAP(k5, k7)   \
  KCSWAP(k0, k1) KCSWAP(k2, k3) KCSWAP(k4, k5) KCSWAP(k6, k7)

// fold sorted d0..d7 into sorted chain k0..k7 (keep low 8 of union)
#define KFOLD8(d0, d1, d2, d3, d4, d5, d6, d7)                  \
  {                                                             \
    k0 = fminf(k0, d7); k1 = fminf(k1, d6);                     \
    k2 = fminf(k2, d5); k3 = fminf(k3, d4);                     \
    k4 = fminf(k4, d3); k5 = fminf(k5, d2);                     \
    k6 = fminf(k6, d1); k7 = fminf(k7, d0);                     \
    KCLEAN8()                                                   \
  }

// Batcher merge with xor-partner's sorted 8 (both sides converge)
#define KMERGE(mv)                                              \
  {                                                             \
    const float q0_ = __shfl_xor(k0, mv, 64);                   \
    const float q1_ = __shfl_xor(k1, mv, 64);                   \
    const float q2_ = __shfl_xor(k2, mv, 64);                   \
    const float q3_ = __shfl_xor(k3, mv, 64);                   \
    const float q4_ = __shfl_xor(k4, mv, 64);                   \
    const float q5_ = __shfl_xor(k5, mv, 64);                   \
    const float q6_ = __shfl_xor(k6, mv, 64);                   \
    const float q7_ = __shfl_xor(k7, mv, 64);                   \
    k0 = fminf(k0, q7_); k1 = fminf(k1, q6_);                   \
    k2 = fminf(k2, q5_); k3 = fminf(k3, q4_);                   \
    k4 = fminf(k4, q3_); k5 = fminf(k5, q2_);                   \
    k6 = fminf(k6, q1_); k7 = fminf(k7, q0_);                   \
    KCLEAN8()                                                   \
  }

// ------------------------- knn (+y, +prep blocks) ---------------------------
// Blocks 0..1023: bb = bid>>7, queries qloc0..+16, 32 lanes/query (sg=t&31),
// slice = cands [sg*64, sg*64+64). Planes xyp/zsp float2[2080], ii=i+(i>>6)
// (lane base sg*65 -> byte stride 520 = 8 mod 128 -> 2-way-free b64 reads).
// Blocks 1024..1055: W-plane prep (fragment order) + C scalars (block 1024).
__global__ __launch_bounds__(512, 4) void knn_kernel(
    const float* __restrict__ x, const float* __restrict__ w0,
    const float* __restrict__ b0, const float* __restrict__ wstk,
    const float* __restrict__ bstk, const float* __restrict__ g,
    const float* __restrict__ be, const float* __restrict__ bm,
    const float* __restrict__ bv, float* __restrict__ ws) {
  __shared__ float2 xyp[2080];
  __shared__ float2 zsp[2080];
  const int t = threadIdx.x;
  const int bid = blockIdx.x;  // 1056

  if (bid >= 1024) {  // ---- prep path (W planes + C scalars) ----
    const int i = (bid - 1024) * 512 + t;  // 16384
    unsigned short* __restrict__ wsh = (unsigned short*)ws;
    const int fo = i >> 7, k = i & 127;
    const float s1 = g[128 + fo] / sqrtf(bv[128 + fo] + EPSF);
    const float s2 = g[256 + fo] / sqrtf(bv[256 + fo] + EPSF);
    unsigned h1, l1, h2, l2;
    split3(wstk[i] * s1, h1, l1);
    split3(wstk[16384 + i] * s2, h2, l2);
    const int dst = ((fo >> 4) * 4 + (k >> 5)) * 512 +
                    (((k >> 3) & 3) * 16 + (fo & 15)) * 8 + (k & 7);
    wsh[OFF16_W1H + dst] = (unsigned short)h1;
    wsh[OFF16_W1L + dst] = (unsigned short)l1;
    wsh[OFF16_W2H + dst] = (unsigned short)h2;
    wsh[OFF16_W2L + dst] = (unsigned short)l2;
    if (bid == 1024 && t < 128) {
      const int f = t;
      const float s0 = g[f] / sqrtf(bv[f] + EPSF);
      const float s1b = g[128 + f] / sqrtf(bv[128 + f] + EPSF);
      const float s2b = g[256 + f] / sqrtf(bv[256 + f] + EPSF);
      ws[OFF_C0 + f] = (b0[f] - bm[f]) * s0 + be[f];
      ws[OFF_C1 + f] = (bstk[f] - bm[128 + f]) * s1b + be[128 + f];
      ws[OFF_C2 + f] = (bstk[128 + f] - bm[256 + f]) * s2b + be[256 + f];
    }
    return;
  }

  const int bb = bid >> 7;
  const int qloc0 = (bid & 127) * 16;
  const float* __restrict__ xb = x + bb * 3 * NN;

  // ---- stage whole batch once ----
#pragma unroll
  for (int k = 0; k < 4; ++k) {
    const int i = t + k * 512;
    const float a0 = xb[i];
    const float a1 = xb[2048 + i];
    const float a2 = xb[4096 + i];
    const float sq = fmaf(a2, a2, fmaf(a1, a1, a0 * a0));
    const int ii = i + (i >> 6);
    xyp[ii] = make_float2(a0, a1);
    zsp[ii] = make_float2(a2, sq);
  }

  const int qi = t >> 5;   // 0..15
  const int sg = t & 31;   // slice
  const int n = qloc0 + qi;
  const int q = bb * NN + n;
  const float qx0 = xb[n], qx1 = xb[2048 + n], qx2 = xb[4096 + n];
  const float sqn = fmaf(qx2, qx2, fmaf(qx1, qx1, qx0 * qx0));

  // ---- y row: features [sg*4, sg*4+4), folded s0 inline (== old prep) ----
  {
    const int f0 = sg * 4;
    float4 yv;
    {
      const float s0 = g[f0] / sqrtf(bv[f0] + EPSF);
      yv.x = fmaf(w0[3 * f0 + 2] * s0, qx2,
                  fmaf(w0[3 * f0 + 1] * s0, qx1, (w0[3 * f0] * s0) * qx0));
    }
    {
      const float s0 = g[f0 + 1] / sqrtf(bv[f0 + 1] + EPSF);
      yv.y = fmaf(w0[3 * f0 + 5] * s0, qx2,
                  fmaf(w0[3 * f0 + 4] * s0, qx1, (w0[3 * f0 + 3] * s0) * qx0));
    }
    {
      const float s0 = g[f0 + 2] / sqrtf(bv[f0 + 2] + EPSF);
      yv.z = fmaf(w0[3 * f0 + 8] * s0, qx2,
                  fmaf(w0[3 * f0 + 7] * s0, qx1, (w0[3 * f0 + 6] * s0) * qx0));
    }
    {
      const float s0 = g[f0 + 3] / sqrtf(bv[f0 + 3] + EPSF);
      yv.w = fmaf(w0[3 * f0 + 11] * s0, qx2,
                  fmaf(w0[3 * f0 + 10] * s0, qx1, (w0[3 * f0 + 9] * s0) * qx0));
    }
    *(float4*)(ws + OFF_Y + (long)q * 128 + f0) = yv;
  }
  __syncthreads();

  const float2* __restrict__ xr = xyp + sg * 65;
  const float2* __restrict__ zr = zsp + sg * 65;

  // ---- phase 1: 8 batches of sort-8 + fold ----
  float k0 = FMAXV, k1 = FMAXV, k2 = FMAXV, k3 = FMAXV,
        k4 = FMAXV, k5 = FMAXV, k6 = FMAXV, k7 = FMAXV;
#pragma unroll
  for (int bt = 0; bt < 8; ++bt) {
    float d0, d1, d2, d3, d4, d5, d6, d7;
#define KD(j, dj)                                                        \
    {                                                                    \
      const float2 cxy = xr[bt * 8 + (j)];                               \
      const float2 czs = zr[bt * 8 + (j)];                               \
      const float inner =                                                \
          fmaf(qx2, czs.x, fmaf(qx1, cxy.y, qx0 * cxy.x));               \
      dj = (sqn - 2.0f * inner) + czs.y;                                 \
    }
    KD(0, d0) KD(1, d1) KD(2, d2) KD(3, d3)
    KD(4, d4) KD(5, d5) KD(6, d6) KD(7, d7)
#undef KD
    SORT8(d0, d1, d2, d3, d4, d5, d6, d7)
    KFOLD8(d0, d1, d2, d3, d4, d5, d6, d7)
  }

  // ---- cross-lane merge: 32 lanes -> exact global 8th-smallest ----
  KMERGE(1) KMERGE(2) KMERGE(4) KMERGE(8) KMERGE(16)
  const float thr = k7;

  // ---- phase 2: recompute-rescan, build hit masks (bit-identical d) ----
  unsigned am = 0, bm2 = 0;
#pragma unroll
  for (int mm = 0; mm < 32; ++mm) {
    const float2 cxy = xr[mm];
    const float2 czs = zr[mm];
    const float inner = fmaf(qx2, czs.x, fmaf(qx1, cxy.y, qx0 * cxy.x));
    const float d = (sqn - 2.0f * inner) + czs.y;
    am |= (d <= thr) ? (1u << mm) : 0u;
  }
#pragma unroll
  for (int mm = 0; mm < 32; ++mm) {
    const float2 cxy = xr[32 + mm];
    const float2 czs = zr[32 + mm];
    const float inner = fmaf(qx2, czs.x, fmaf(qx1, cxy.y, qx0 * cxy.x));
    const float d = (sqn - 2.0f * inner) + czs.y;
    bm2 |= (d <= thr) ? (1u << mm) : 0u;
  }

  // ---- exclusive scan of per-lane counts over the 32-lane group ----
  const int cnt = __popc(am) + __popc(bm2);
  int inc = cnt, tq;
  tq = __shfl_up(inc, 1, 32); inc += (sg >= 1) ? tq : 0;
  tq = __shfl_up(inc, 2, 32); inc += (sg >= 2) ? tq : 0;
  tq = __shfl_up(inc, 4, 32); inc += (sg >= 4) ? tq : 0;
  tq = __shfl_up(inc, 8, 32); inc += (sg >= 8) ? tq : 0;
  tq = __shfl_up(inc, 16, 32); inc += (sg >= 16) ? tq : 0;
  int pos = inc - cnt;

  // ---- extraction: hits in ascending candidate index (lane-major) ----
  int* __restrict__ idxg = (int*)(ws + OFF_IDX);
  {
    unsigned w = am;
    while (w) {
      const int b = __ffs(w) - 1;
      w &= w - 1;
      if (pos < 8) idxg[q * 8 + pos] = bb * NN + sg * 64 + b;
      ++pos;
    }
    w = bm2;
    while (w) {
      const int b = __ffs(w) - 1;
      w &= w - 1;
      if (pos < 8) idxg[q * 8 + pos] = bb * NN + sg * 64 + 32 + b;
      ++pos;
    }
  }
}

// --------------------------- persistent fused ------------------------------
// 256 blocks x 512 thr (8 waves: wr=w>>2 pair-half, wc=w&3 fo-slice).
// Block bid: batch bb=bid&7, queries qseg*64..+64 (qseg=bid>>3), 8 chunks of
// 64 pairs. LDS 128KB: A dbuf 2x32KB @0, H 32KB @64K, OS 32KB @96K.
// A-plane 16B chunks swizzled col = kc ^ (row&7); H 16B chunks cc ^= (p&7).
__global__ __launch_bounds__(512, 2) void fused_kernel(float* __restrict__ ws,
                                                       float* __restrict__ out) {
  extern __shared__ char smem[];
  unsigned* __restrict__ H = (unsigned*)(smem + 65536);
  float* __restrict__ OS = (float*)(smem + 98304);

  const float* __restrict__ y = ws + OFF_Y;
  const int* __restrict__ idxg = (const int*)(ws + OFF_IDX);
  const unsigned short* __restrict__ wsu = (const unsigned short*)ws;

  const int t = threadIdx.x;
  const int lane = t & 63, w = t >> 6;
  const int wr = w >> 2, wc = w & 3;
  const int bid = blockIdx.x;
  const int bb = bid & 7, qseg = bid >> 3;
  const int chunk0 = bb * 256 + qseg * 8;

  // ---- W fragments -> registers (once; coalesced 1KB/wave frag loads) ----
  short8v w1h[2][4], w1l[2][4], w2h[2][4], w2l[2][4];
#pragma unroll
  for (int ft = 0; ft < 2; ++ft)
#pragma unroll
    for (int ks = 0; ks < 4; ++ks) {
      const int off = ((wc * 2 + ft) * 4 + ks) * 512 + lane * 8;
      w1h[ft][ks] = *(const short8v*)(wsu + OFF16_W1H + off);
      w1l[ft][ks] = *(const short8v*)(wsu + OFF16_W1L + off);
      w2h[ft][ks] = *(const short8v*)(wsu + OFF16_W2H + off);
      w2l[ft][ks] = *(const short8v*)(wsu + OFF16_W2L + off);
    }

  const float c1v0 = (ws + OFF_C1)[wc * 32 + (lane & 15)];
  const float c1v1 = (ws + OFF_C1)[wc * 32 + 16 + (lane & 15)];
  const float c2v0 = (ws + OFF_C2)[wc * 32 + (lane & 15)];
  const float c2v1 = (ws + OFF_C2)[wc * 32 + 16 + (lane & 15)];

  // ---- per-thread A-staging constants ----
  const int row = t >> 3, part8 = t & 7;
  const float* __restrict__ c0p = ws + OFF_C0 + part8 * 16;
  const float4 c0a = *(const float4*)(c0p + 0);
  const float4 c0b = *(const float4*)(c0p + 4);
  const float4 c0c = *(const float4*)(c0p + 8);
  const float4 c0d = *(const float4*)(c0p + 12);

// pack 8 floats (relu'd h1 values) into hi/lo int4 and write swizzled
#define PACK_WRITE_A(base, hv, kc)                              \
  {                                                             \
    unsigned hh[8], ll[8];                                      \
    _Pragma("unroll") for (int e = 0; e < 8; ++e)               \
        split3(hv[e], hh[e], ll[e]);                            \
    int4 hp, lp;                                                \
    hp.x = (int)(hh[0] | (hh[1] << 16));                        \
    hp.y = (int)(hh[2] | (hh[3] << 16));                        \
    hp.z = (int)(hh[4] | (hh[5] << 16));                        \
    hp.w = (int)(hh[6] | (hh[7] << 16));                        \
    lp.x = (int)(ll[0] | (ll[1] << 16));                        \
    lp.y = (int)(ll[2] | (ll[3] << 16));                        \
    lp.z = (int)(ll[4] | (ll[5] << 16));                        \
    lp.w = (int)(ll[6] | (ll[7] << 16));                        \
    const int col = (kc) ^ (row & 7);                           \
    *(int4*)((base) + row * 256 + col * 16) = hp;               \
    *(int4*)((base) + 16384 + row * 256 + col * 16) = lp;       \
  }

  // ---- prologue: stage A[0] into buf0 ----
  {
    const int gp = chunk0 * 64 + row;
    const int mg = idxg[gp];
    const float* __restrict__ ym = y + (long)mg * 128 + part8 * 16;
    const float* __restrict__ yn = y + (long)(gp >> 3) * 128 + part8 * 16;
    const float4 a0 = *(const float4*)(ym + 0);
    const float4 a1 = *(const float4*)(ym + 4);
    const float4 a2 = *(const float4*)(ym + 8);
    const float4 a3 = *(const float4*)(ym + 12);
    const float4 n0 = *(const float4*)(yn + 0);
    const float4 n1 = *(const float4*)(yn + 4);
    const float4 n2 = *(const float4*)(yn + 8);
    const float4 n3 = *(const float4*)(yn + 12);
    float hv0[8] = {relu_f(a0.x - n0.x + c0a.x), relu_f(a0.y - n0.y + c0a.y),
                    relu_f(a0.z - n0.z + c0a.z), relu_f(a0.w - n0.w + c0a.w),
                    relu_f(a1.x - n1.x + c0b.x), relu_f(a1.y - n1.y + c0b.y),
                    relu_f(a1.z - n1.z + c0b.z), relu_f(a1.w - n1.w + c0b.w)};
    float hv1[8] = {relu_f(a2.x - n2.x + c0c.x), relu_f(a2.y - n2.y + c0c.y),
                    relu_f(a2.z - n2.z + c0c.z), relu_f(a2.w - n2.w + c0c.w),
                    relu_f(a3.x - n3.x + c0d.x), relu_f(a3.y - n3.y + c0d.y),
                    relu_f(a3.z - n3.z + c0d.z), relu_f(a3.w - n3.w + c0d.w)};
    PACK_WRITE_A(smem, hv0, part8 * 2)
    PACK_WRITE_A(smem, hv1, part8 * 2 + 1)
  }
  __syncthreads();

#pragma unroll 1
  for (int j = 0; j < 8; ++j) {
    char* __restrict__ Acur = smem + (j & 1) * 32768;
    char* __restrict__ Anxt = smem + ((j & 1) ^ 1) * 32768;

    int mg_next = 0, gp_next = 0;
    if (j < 7) {
      gp_next = (chunk0 + j + 1) * 64 + row;
      mg_next = idxg[gp_next];
    }

    // ---- g1: acc = h1 . W1^T (bf16x3), A from Acur ----
    f32x4 acc[2][2];
#pragma unroll
    for (int pt = 0; pt < 2; ++pt)
#pragma unroll
      for (int ft = 0; ft < 2; ++ft) acc[pt][ft] = (f32x4){0.f, 0.f, 0.f, 0.f};
#pragma unroll
    for (int ks = 0; ks < 4; ++ks) {
      const int kc = ks * 4 + (lane >> 4);
#pragma unroll
      for (int pt = 0; pt < 2; ++pt) {
        const int arow = wr * 32 + pt * 16 + (lane & 15);
        const int col = kc ^ (arow & 7);
        const short8v ah = *(const short8v*)(Acur + arow * 256 + col * 16);
        const short8v al =
            *(const short8v*)(Acur + 16384 + arow * 256 + col * 16);
#pragma unroll
        for (int ft = 0; ft < 2; ++ft) {
          acc[pt][ft] = mfma16x16x32bf(al, w1h[ft][ks], acc[pt][ft]);
          acc[pt][ft] = mfma16x16x32bf(ah, w1l[ft][ks], acc[pt][ft]);
          acc[pt][ft] = mfma16x16x32bf(ah, w1h[ft][ks], acc[pt][ft]);
        }
      }
    }

    // ---- issue next chunk's y loads (latency hides under H + g2) ----
    float4 a0, a1, a2, a3, n0, n1, n2, n3;
    if (j < 7) {
      const float* __restrict__ ym = y + (long)mg_next * 128 + part8 * 16;
      const float* __restrict__ yn = y + (long)(gp_next >> 3) * 128 + part8 * 16;
      a0 = *(const float4*)(ym + 0);
      a1 = *(const float4*)(ym + 4);
      a2 = *(const float4*)(ym + 8);
      a3 = *(const float4*)(ym + 12);
      n0 = *(const float4*)(yn + 0);
      n1 = *(const float4*)(yn + 4);
      n2 = *(const float4*)(yn + 8);
      n3 = *(const float4*)(yn + 12);
    }

    // ---- g1 epilogue: relu(acc+c1) -> H (packed u32, swizzled) ----
#pragma unroll
    for (int pt = 0; pt < 2; ++pt)
#pragma unroll
      for (int ft = 0; ft < 2; ++ft) {
        const int fo = wc * 32 + ft * 16 + (lane & 15);
        const int cc = fo >> 2;
        const float cb = ft ? c1v1 : c1v0;
#pragma unroll
        for (int reg = 0; reg < 4; ++reg) {
          const int p = wr * 32 + pt * 16 + (lane >> 4) * 4 + reg;
          const float vv = relu_f(acc[pt][ft][reg] + cb);
          unsigned hh, ll;
          split3(vv, hh, ll);
          H[p * 128 + ((cc ^ (p & 7)) << 2) + (fo & 3)] = (hh << 16) | ll;
        }
      }
    __syncthreads();  // H ready

    // ---- g2: acc2 = h2 . W2^T (bf16x3), A from H ----
    f32x4 acc2[2][2];
#pragma unroll
    for (int pt = 0; pt < 2; ++pt)
#pragma unroll
      for (int ft = 0; ft < 2; ++ft) acc2[pt][ft] = (f32x4){0.f, 0.f, 0.f, 0.f};
#pragma unroll
    for (int ks = 0; ks < 4; ++ks) {
      const int cc0 = ks * 8 + (lane >> 4) * 2;
#pragma unroll
      for (int pt = 0; pt < 2; ++pt) {
        const int p = wr * 32 + pt * 16 + (lane & 15);
        const int4 u0 = *(const int4*)&H[p * 128 + ((cc0 ^ (p & 7)) << 2)];
        const int4 u1 = *(const int4*)&H[p * 128 + (((cc0 + 1) ^ (p & 7)) << 2)];
        const unsigned uu[8] = {(unsigned)u0.x, (unsigned)u0.y, (unsigned)u0.z,
                                (unsigned)u0.w, (unsigned)u1.x, (unsigned)u1.y,
                                (unsigned)u1.z, (unsigned)u1.w};
        short8v ah, al;
#pragma unroll
        for (int e = 0; e < 8; ++e) {
          ah[e] = (short)(uu[e] >> 16);
          al[e] = (short)(uu[e] & 0xFFFFu);
        }
#pragma unroll
        for (int ft = 0; ft < 2; ++ft) {
          acc2[pt][ft] = mfma16x16x32bf(al, w2h[ft][ks], acc2[pt][ft]);
          acc2[pt][ft] = mfma16x16x32bf(ah, w2l[ft][ks], acc2[pt][ft]);
          acc2[pt][ft] = mfma16x16x32bf(ah, w2h[ft][ks], acc2[pt][ft]);
        }
      }
    }
    __syncthreads();  // H reads done (next iter may overwrite H)

    // ---- g2 epilogue: relu+max over 8 pairs/query -> OS rows j*8.. ----
    {
      const int g = lane >> 4;
#pragma unroll
      for (int pt = 0; pt < 2; ++pt)
#pragma unroll
        for (int ft = 0; ft < 2; ++ft) {
          const int fo = wc * 32 + ft * 16 + (lane & 15);
          const float cb = ft ? c2v1 : c2v0;
          const float v0 = relu_f(acc2[pt][ft][0] + cb);
          const float v1 = relu_f(acc2[pt][ft][1] + cb);
          const float v2 = relu_f(acc2[pt][ft][2] + cb);
          const float v3 = relu_f(acc2[pt][ft][3] + cb);
          float m = fmaxf(fmaxf(v0, v1), fmaxf(v2, v3));
          m = fmaxf(m, __shfl_xor(m, 16, 64));
          if ((g & 1) == 0) {
            const int qloc = wr * 4 + pt * 2 + (g >> 1);
            OS[(j * 8 + qloc) * 128 + fo] = m;
          }
        }
    }

    // ---- pack & write A[j+1] into Anxt (loads returned during g2) ----
    if (j < 7) {
      float hv0[8] = {relu_f(a0.x - n0.x + c0a.x), relu_f(a0.y - n0.y + c0a.y),
                      relu_f(a0.z - n0.z + c0a.z), relu_f(a0.w - n0.w + c0a.w),
                      relu_f(a1.x - n1.x + c0b.x), relu_f(a1.y - n1.y + c0b.y),
                      relu_f(a1.z - n1.z + c0b.z), relu_f(a1.w - n1.w + c0b.w)};
      float hv1[8] = {relu_f(a2.x - n2.x + c0c.x), relu_f(a2.y - n2.y + c0c.y),
                      relu_f(a2.z - n2.z + c0c.z), relu_f(a2.w - n2.w + c0c.w),
                      relu_f(a3.x - n3.x + c0d.x), relu_f(a3.y - n3.y + c0d.y),
                      relu_f(a3.z - n3.z + c0d.z), relu_f(a3.w - n3.w + c0d.w)};
      PACK_WRITE_A(Anxt, hv0, part8 * 2)
      PACK_WRITE_A(Anxt, hv1, part8 * 2 + 1)
    }
    __syncthreads();  // A[j+1] ready; OS rows settled
  }

  // ---- final coalesced out-write: OS[64][128] -> out[bb][f][qseg*64..] ----
  {
    const int f = t >> 2, seg = t & 3;
    float* __restrict__ op = out + (long)(bb * 128 + f) * 2048 + qseg * 64 + seg * 16;
#pragma unroll
    for (int u = 0; u < 4; ++u) {
      float4 o;
      o.x = OS[(seg * 16 + u * 4 + 0) * 128 + f];
      o.y = OS[(seg * 16 + u * 4 + 1) * 128 + f];
      o.z = OS[(seg * 16 + u * 4 + 2) * 128 + f];
      o.w = OS[(seg * 16 + u * 4 + 3) * 128 + f];
      *(float4*)(op + u * 4) = o;
    }
  }
}

// ------------------------------- launch ------------------------------------
extern "C" void kernel_launch(void* const* d_in, const int* in_sizes, int n_in,
                              void* d_out, int out_size, void* d_ws,
                              size_t ws_size, hipStream_t stream) {
  (void)in_sizes; (void)n_in; (void)out_size; (void)ws_size;
  const float* x = (const float*)d_in[0];
  const float* w0 = (const float*)d_in[1];
  const float* b0 = (const float*)d_in[2];
  const float* wst = (const float*)d_in[3];
  const float* bst = (const float*)d_in[4];
  const float* g = (const float*)d_in[5];
  const float* be = (const float*)d_in[6];
  const float* bm = (const float*)d_in[7];
  const float* bv = (const float*)d_in[8];
  float* out = (float*)d_out;
  float* ws = (float*)d_ws;

  hipFuncSetAttribute((const void*)fused_kernel,
                      hipFuncAttributeMaxDynamicSharedMemorySize, 131072);

  knn_kernel<<<1056, 512, 0, stream>>>(x, w0, b0, wst, bst, g, be, bm, bv, ws);
  fused_kernel<<<256, 512, 131072, stream>>>(ws, out);
}

// Round 12
// 75.029 us; speedup vs baseline: 1.1153x; 1.0028x over previous
//
#include <hip/hip_runtime.h>

// ---------------------------------------------------------------------------
// FeatureNet: kNN(K=8) relative grouping -> [conv1x1+BN+ReLU] x3 -> max over K
// B=8, N=2048, DIM=128, fp32 in/out.
//
// knn  : R11 (unchanged): 1056 blocks x 512 thr; batch staged once in split
//        float2 planes; sort8+fold phase1; 5 merge rounds -> exact threshold;
//        mask rescan -> idx[q][8]; y from raw w0/g/bv; prep blocks 1024+.
// fused: R12: 512 blocks x 256 thr (4 waves), chunk = 32 pairs, LDS 64KB
//        (A dbuf 2x16K @0, H 16K @32K, OS 16K @48K). VGPR ~200 -> 8 waves/CU
//        = TWO independent 4-wave blocks per CU whose phases interleave
//        (replaces R6's single 8-wave lockstep block; barrier drains now
//        covered by the co-resident block). W in 128 VGPRs as before.
// ---------------------------------------------------------------------------

#define EPSF 1e-5f
#define FMAXV 3.402823466e+38f

#define NB 8
#define NN 2048
#define KNBR 8
#define DIMF 128
#define NQ (NB * NN)        // 16384
#define NPAIR (NQ * KNBR)   // 131072

// ws layout. W planes in u16 units [0, 65536) == floats [0, 32768).
#define OFF16_W1H 0          // 16384 u16 (fragment order)
#define OFF16_W1L 16384
#define OFF16_W2H 32768
#define OFF16_W2L 49152
#define OFF_C0 32768         // float units
#define OFF_C1 32896
#define OFF_C2 33024
#define OFF_Y 33792          // 2097152 floats
#define OFF_IDX (OFF_Y + NQ * DIMF)   // 131072 ints

typedef __attribute__((ext_vector_type(4))) float f32x4;
typedef __attribute__((ext_vector_type(8))) short short8v;

__device__ __forceinline__ float relu_f(float a) { return fmaxf(a, 0.0f); }

// fp32 -> bf16(hi, RNE) + bf16(lo, trunc of residual)
__device__ __forceinline__ void split3(float f, unsigned& hi, unsigned& lo) {
  const unsigned u = __float_as_uint(f);
  const unsigned h = (u + 0x7FFFu + ((u >> 16) & 1u)) >> 16;
  const float hf = __uint_as_float(h << 16);
  lo = __float_as_uint(f - hf) >> 16;
  hi = h;
}

__device__ __forceinline__ f32x4 mfma16x16x32bf(short8v a, short8v b, f32x4 c) {
  return __builtin_amdgcn_mfma_f32_16x16x32_bf16(a, b, c, 0, 0, 0);
}

// ---- named-scalar selection primitives (R7 lesson: NO array state) ----
#define KCSWAP(a, b)                  \
  {                                   \
    const float mn_ = fminf(a, b);    \
    const float mx_ = fmaxf(a, b);    \
    (a) = mn_; (b) = mx_;             \
  }

// Batcher odd-even mergesort of 8 keys (19 comparators), ascending
#define SORT8(d0, d1, d2, d3, d4, d5, d6, d7)                   \
  KCSWAP(d0, d1) KCSWAP(d2, d3) KCSWAP(d4, d5) KCSWAP(d6, d7)   \
  KCSWAP(d0, d2) KCSWAP(d1, d3) KCSWAP(d4, d6) KCSWAP(d5, d7)   \
  KCSWAP(d1, d2) KCSWAP(d5, d6)                                 \
  KCSWAP(d0, d4) KCSWAP(d1, d5) KCSWAP(d2, d6) KCSWAP(d3, d7)   \
  KCSWAP(d2, d4) KCSWAP(d3, d5)                                 \
  KCSWAP(d1, d2) KCSWAP(d3, d4) KCSWAP(d5, d6)

// 3-stage bitonic cleanup of a bitonic 8-seq in k0..k7 (sorts ascending)
#define KCLEAN8()                                               \
  KCSWAP(k0, k4) KCSWAP(k1, k5) KCSWAP(k2, k6) KCSWAP(k3, k7)   \
  KCSWAP(k0, k2) KCSWAP(k1, k3) KCSWAP(k4, k6) KCSWAP(k5, k7)   \
  KCSWAP(k0, k1) KCSWAP(k2, k3) KCSWAP(k4, k5) KCSWAP(k6, k7)

// fold sorted d0..d7 into sorted chain k0..k7 (keep low 8 of union)
#define KFOLD8(d0, d1, d2, d3, d4, d5, d6, d7)                  \
  {                                                             \
    k0 = fminf(k0, d7); k1 = fminf(k1, d6);                     \
    k2 = fminf(k2, d5); k3 = fminf(k3, d4);                     \
    k4 = fminf(k4, d3); k5 = fminf(k5, d2);                     \
    k6 = fminf(k6, d1); k7 = fminf(k7, d0);                     \
    KCLEAN8()                                                   \
  }

// Batcher merge with xor-partner's sorted 8 (both sides converge)
#define KMERGE(mv)                                              \
  {                                                             \
    const float q0_ = __shfl_xor(k0, mv, 64);                   \
    const float q1_ = __shfl_xor(k1, mv, 64);                   \
    const float q2_ = __shfl_xor(k2, mv, 64);                   \
    const float q3_ = __shfl_xor(k3, mv, 64);                   \
    const float q4_ = __shfl_xor(k4, mv, 64);                   \
    const float q5_ = __shfl_xor(k5, mv, 64);                   \
    const float q6_ = __shfl_xor(k6, mv, 64);                   \
    const float q7_ = __shfl_xor(k7, mv, 64);                   \
    k0 = fminf(k0, q7_); k1 = fminf(k1, q6_);                   \
    k2 = fminf(k2, q5_); k3 = fminf(k3, q4_);                   \
    k4 = fminf(k4, q3_); k5 = fminf(k5, q2_);                   \
    k6 = fminf(k6, q1_); k7 = fminf(k7, q0_);                   \
    KCLEAN8()                                                   \
  }

// ------------------------- knn (+y, +prep blocks) ---------------------------
// Blocks 0..1023: bb = bid>>7, queries qloc0..+16, 32 lanes/query (sg=t&31),
// slice = cands [sg*64, sg*64+64). Planes xyp/zsp float2[2080], ii=i+(i>>6)
// (lane base sg*65 -> byte stride 520 = 8 mod 128 -> 2-way-free b64 reads).
// Blocks 1024..1055: W-plane prep (fragment order) + C scalars (block 1024).
__global__ __launch_bounds__(512, 4) void knn_kernel(
    const float* __restrict__ x, const float* __restrict__ w0,
    const float* __restrict__ b0, const float* __restrict__ wstk,
    const float* __restrict__ bstk, const float* __restrict__ g,
    const float* __restrict__ be, const float* __restrict__ bm,
    const float* __restrict__ bv, float* __restrict__ ws) {
  __shared__ float2 xyp[2080];
  __shared__ float2 zsp[2080];
  const int t = threadIdx.x;
  const int bid = blockIdx.x;  // 1056

  if (bid >= 1024) {  // ---- prep path (W planes + C scalars) ----
    const int i = (bid - 1024) * 512 + t;  // 16384
    unsigned short* __restrict__ wsh = (unsigned short*)ws;
    const int fo = i >> 7, k = i & 127;
    const float s1 = g[128 + fo] / sqrtf(bv[128 + fo] + EPSF);
    const float s2 = g[256 + fo] / sqrtf(bv[256 + fo] + EPSF);
    unsigned h1, l1, h2, l2;
    split3(wstk[i] * s1, h1, l1);
    split3(wstk[16384 + i] * s2, h2, l2);
    const int dst = ((fo >> 4) * 4 + (k >> 5)) * 512 +
                    (((k >> 3) & 3) * 16 + (fo & 15)) * 8 + (k & 7);
    wsh[OFF16_W1H + dst] = (unsigned short)h1;
    wsh[OFF16_W1L + dst] = (unsigned short)l1;
    wsh[OFF16_W2H + dst] = (unsigned short)h2;
    wsh[OFF16_W2L + dst] = (unsigned short)l2;
    if (bid == 1024 && t < 128) {
      const int f = t;
      const float s0 = g[f] / sqrtf(bv[f] + EPSF);
      const float s1b = g[128 + f] / sqrtf(bv[128 + f] + EPSF);
      const float s2b = g[256 + f] / sqrtf(bv[256 + f] + EPSF);
      ws[OFF_C0 + f] = (b0[f] - bm[f]) * s0 + be[f];
      ws[OFF_C1 + f] = (bstk[f] - bm[128 + f]) * s1b + be[128 + f];
      ws[OFF_C2 + f] = (bstk[128 + f] - bm[256 + f]) * s2b + be[256 + f];
    }
    return;
  }

  const int bb = bid >> 7;
  const int qloc0 = (bid & 127) * 16;
  const float* __restrict__ xb = x + bb * 3 * NN;

  // ---- stage whole batch once ----
#pragma unroll
  for (int k = 0; k < 4; ++k) {
    const int i = t + k * 512;
    const float a0 = xb[i];
    const float a1 = xb[2048 + i];
    const float a2 = xb[4096 + i];
    const float sq = fmaf(a2, a2, fmaf(a1, a1, a0 * a0));
    const int ii = i + (i >> 6);
    xyp[ii] = make_float2(a0, a1);
    zsp[ii] = make_float2(a2, sq);
  }

  const int qi = t >> 5;   // 0..15
  const int sg = t & 31;   // slice
  const int n = qloc0 + qi;
  const int q = bb * NN + n;
  const float qx0 = xb[n], qx1 = xb[2048 + n], qx2 = xb[4096 + n];
  const float sqn = fmaf(qx2, qx2, fmaf(qx1, qx1, qx0 * qx0));

  // ---- y row: features [sg*4, sg*4+4), folded s0 inline (== old prep) ----
  {
    const int f0 = sg * 4;
    float4 yv;
    {
      const float s0 = g[f0] / sqrtf(bv[f0] + EPSF);
      yv.x = fmaf(w0[3 * f0 + 2] * s0, qx2,
                  fmaf(w0[3 * f0 + 1] * s0, qx1, (w0[3 * f0] * s0) * qx0));
    }
    {
      const float s0 = g[f0 + 1] / sqrtf(bv[f0 + 1] + EPSF);
      yv.y = fmaf(w0[3 * f0 + 5] * s0, qx2,
                  fmaf(w0[3 * f0 + 4] * s0, qx1, (w0[3 * f0 + 3] * s0) * qx0));
    }
    {
      const float s0 = g[f0 + 2] / sqrtf(bv[f0 + 2] + EPSF);
      yv.z = fmaf(w0[3 * f0 + 8] * s0, qx2,
                  fmaf(w0[3 * f0 + 7] * s0, qx1, (w0[3 * f0 + 6] * s0) * qx0));
    }
    {
      const float s0 = g[f0 + 3] / sqrtf(bv[f0 + 3] + EPSF);
      yv.w = fmaf(w0[3 * f0 + 11] * s0, qx2,
                  fmaf(w0[3 * f0 + 10] * s0, qx1, (w0[3 * f0 + 9] * s0) * qx0));
    }
    *(float4*)(ws + OFF_Y + (long)q * 128 + f0) = yv;
  }
  __syncthreads();

  const float2* __restrict__ xr = xyp + sg * 65;
  const float2* __restrict__ zr = zsp + sg * 65;

  // ---- phase 1: 8 batches of sort-8 + fold ----
  float k0 = FMAXV, k1 = FMAXV, k2 = FMAXV, k3 = FMAXV,
        k4 = FMAXV, k5 = FMAXV, k6 = FMAXV, k7 = FMAXV;
#pragma unroll
  for (int bt = 0; bt < 8; ++bt) {
    float d0, d1, d2, d3, d4, d5, d6, d7;
#define KD(j, dj)                                                        \
    {                                                                    \
      const float2 cxy = xr[bt * 8 + (j)];                               \
      const float2 czs = zr[bt * 8 + (j)];                               \
      const float inner =                                                \
          fmaf(qx2, czs.x, fmaf(qx1, cxy.y, qx0 * cxy.x));               \
      dj = (sqn - 2.0f * inner) + czs.y;                                 \
    }
    KD(0, d0) KD(1, d1) KD(2, d2) KD(3, d3)
    KD(4, d4) KD(5, d5) KD(6, d6) KD(7, d7)
#undef KD
    SORT8(d0, d1, d2, d3, d4, d5, d6, d7)
    KFOLD8(d0, d1, d2, d3, d4, d5, d6, d7)
  }

  // ---- cross-lane merge: 32 lanes -> exact global 8th-smallest ----
  KMERGE(1) KMERGE(2) KMERGE(4) KMERGE(8) KMERGE(16)
  const float thr = k7;

  // ---- phase 2: recompute-rescan, build hit masks (bit-identical d) ----
  unsigned am = 0, bm2 = 0;
#pragma unroll
  for (int mm = 0; mm < 32; ++mm) {
    const float2 cxy = xr[mm];
    const float2 czs = zr[mm];
    const float inner = fmaf(qx2, czs.x, fmaf(qx1, cxy.y, qx0 * cxy.x));
    const float d = (sqn - 2.0f * inner) + czs.y;
    am |= (d <= thr) ? (1u << mm) : 0u;
  }
#pragma unroll
  for (int mm = 0; mm < 32; ++mm) {
    const float2 cxy = xr[32 + mm];
    const float2 czs = zr[32 + mm];
    const float inner = fmaf(qx2, czs.x, fmaf(qx1, cxy.y, qx0 * cxy.x));
    const float d = (sqn - 2.0f * inner) + czs.y;
    bm2 |= (d <= thr) ? (1u << mm) : 0u;
  }

  // ---- exclusive scan of per-lane counts over the 32-lane group ----
  const int cnt = __popc(am) + __popc(bm2);
  int inc = cnt, tq;
  tq = __shfl_up(inc, 1, 32); inc += (sg >= 1) ? tq : 0;
  tq = __shfl_up(inc, 2, 32); inc += (sg >= 2) ? tq : 0;
  tq = __shfl_up(inc, 4, 32); inc += (sg >= 4) ? tq : 0;
  tq = __shfl_up(inc, 8, 32); inc += (sg >= 8) ? tq : 0;
  tq = __shfl_up(inc, 16, 32); inc += (sg >= 16) ? tq : 0;
  int pos = inc - cnt;

  // ---- extraction: hits in ascending candidate index (lane-major) ----
  int* __restrict__ idxg = (int*)(ws + OFF_IDX);
  {
    unsigned w = am;
    while (w) {
      const int b = __ffs(w) - 1;
      w &= w - 1;
      if (pos < 8) idxg[q * 8 + pos] = bb * NN + sg * 64 + b;
      ++pos;
    }
    w = bm2;
    while (w) {
      const int b = __ffs(w) - 1;
      w &= w - 1;
      if (pos < 8) idxg[q * 8 + pos] = bb * NN + sg * 64 + 32 + b;
      ++pos;
    }
  }
}

// --------------------------- persistent fused ------------------------------
// R12: 512 blocks x 256 thr (4 waves, wc = w = fo-slice). Block bid:
// batch bb=bid&7, qseg=bid>>3 (0..63, 32 queries), 8 chunks of 32 pairs.
// LDS 64KB: A dbuf 2x16KB @0 (hi 8K + lo 8K each), H 16KB @32K, OS 16KB @48K.
// Two blocks co-resident per CU (VGPR ~200 -> 8 waves) -> phases interleave.
// A-plane 16B chunks swizzled col = kc ^ (row&7); H 16B chunks cc ^= (p&7).
__global__ __launch_bounds__(256, 2) void fused_kernel(float* __restrict__ ws,
                                                       float* __restrict__ out) {
  extern __shared__ char smem[];
  unsigned* __restrict__ H = (unsigned*)(smem + 32768);
  float* __restrict__ OS = (float*)(smem + 49152);

  const float* __restrict__ y = ws + OFF_Y;
  const int* __restrict__ idxg = (const int*)(ws + OFF_IDX);
  const unsigned short* __restrict__ wsu = (const unsigned short*)ws;

  const int t = threadIdx.x;
  const int lane = t & 63, w = t >> 6;
  const int wc = w;  // 4 waves = 4 fo-slices of 32
  const int bid = blockIdx.x;
  const int bb = bid & 7, qseg = bid >> 3;      // qseg 0..63
  const int chunk0 = bb * 512 + qseg * 8;       // 32-pair chunks

  // ---- W fragments -> registers (once; coalesced 1KB/wave frag loads) ----
  short8v w1h[2][4], w1l[2][4], w2h[2][4], w2l[2][4];
#pragma unroll
  for (int ft = 0; ft < 2; ++ft)
#pragma unroll
    for (int ks = 0; ks < 4; ++ks) {
      const int off = ((wc * 2 + ft) * 4 + ks) * 512 + lane * 8;
      w1h[ft][ks] = *(const short8v*)(wsu + OFF16_W1H + off);
      w1l[ft][ks] = *(const short8v*)(wsu + OFF16_W1L + off);
      w2h[ft][ks] = *(const short8v*)(wsu + OFF16_W2H + off);
      w2l[ft][ks] = *(const short8v*)(wsu + OFF16_W2L + off);
    }

  const float c1v0 = (ws + OFF_C1)[wc * 32 + (lane & 15)];
  const float c1v1 = (ws + OFF_C1)[wc * 32 + 16 + (lane & 15)];
  const float c2v0 = (ws + OFF_C2)[wc * 32 + (lane & 15)];
  const float c2v1 = (ws + OFF_C2)[wc * 32 + 16 + (lane & 15)];

  // ---- per-thread A-staging constants (row 0..31, 16 floats each) ----
  const int row = t >> 3, part8 = t & 7;
  const float* __restrict__ c0p = ws + OFF_C0 + part8 * 16;
  const float4 c0a = *(const float4*)(c0p + 0);
  const float4 c0b = *(const float4*)(c0p + 4);
  const float4 c0c = *(const float4*)(c0p + 8);
  const float4 c0d = *(const float4*)(c0p + 12);

// pack 8 floats into hi/lo int4, write swizzled (lo plane at +8192)
#define PACK_WRITE_A(base, hv, kc)                              \
  {                                                             \
    unsigned hh[8], ll[8];                                      \
    _Pragma("unroll") for (int e = 0; e < 8; ++e)               \
        split3(hv[e], hh[e], ll[e]);                            \
    int4 hp, lp;                                                \
    hp.x = (int)(hh[0] | (hh[1] << 16));                        \
    hp.y = (int)(hh[2] | (hh[3] << 16));                        \
    hp.z = (int)(hh[4] | (hh[5] << 16));                        \
    hp.w = (int)(hh[6] | (hh[7] << 16));                        \
    lp.x = (int)(ll[0] | (ll[1] << 16));                        \
    lp.y = (int)(ll[2] | (ll[3] << 16));                        \
    lp.z = (int)(ll[4] | (ll[5] << 16));                        \
    lp.w = (int)(ll[6] | (ll[7] << 16));                        \
    const int col = (kc) ^ (row & 7);                           \
    *(int4*)((base) + row * 256 + col * 16) = hp;               \
    *(int4*)((base) + 8192 + row * 256 + col * 16) = lp;        \
  }

  // ---- prologue: stage A[0] into buf0 ----
  {
    const int gp = chunk0 * 32 + row;
    const int mg = idxg[gp];
    const float* __restrict__ ym = y + (long)mg * 128 + part8 * 16;
    const float* __restrict__ yn = y + (long)(gp >> 3) * 128 + part8 * 16;
    const float4 a0 = *(const float4*)(ym + 0);
    const float4 a1 = *(const float4*)(ym + 4);
    const float4 a2 = *(const float4*)(ym + 8);
    const float4 a3 = *(const float4*)(ym + 12);
    const float4 n0 = *(const float4*)(yn + 0);
    const float4 n1 = *(const float4*)(yn + 4);
    const float4 n2 = *(const float4*)(yn + 8);
    const float4 n3 = *(const float4*)(yn + 12);
    float hv0[8] = {relu_f(a0.x - n0.x + c0a.x), relu_f(a0.y - n0.y + c0a.y),
                    relu_f(a0.z - n0.z + c0a.z), relu_f(a0.w - n0.w + c0a.w),
                    relu_f(a1.x - n1.x + c0b.x), relu_f(a1.y - n1.y + c0b.y),
                    relu_f(a1.z - n1.z + c0b.z), relu_f(a1.w - n1.w + c0b.w)};
    float hv1[8] = {relu_f(a2.x - n2.x + c0c.x), relu_f(a2.y - n2.y + c0c.y),
                    relu_f(a2.z - n2.z + c0c.z), relu_f(a2.w - n2.w + c0c.w),
                    relu_f(a3.x - n3.x + c0d.x), relu_f(a3.y - n3.y + c0d.y),
                    relu_f(a3.z - n3.z + c0d.z), relu_f(a3.w - n3.w + c0d.w)};
    PACK_WRITE_A(smem, hv0, part8 * 2)
    PACK_WRITE_A(smem, hv1, part8 * 2 + 1)
  }
  __syncthreads();

#pragma unroll 1
  for (int j = 0; j < 8; ++j) {
    char* __restrict__ Acur = smem + (j & 1) * 16384;
    char* __restrict__ Anxt = smem + ((j & 1) ^ 1) * 16384;

    int mg_next = 0, gp_next = 0;
    if (j < 7) {
      gp_next = (chunk0 + j + 1) * 32 + row;
      mg_next = idxg[gp_next];
    }

    // ---- g1: acc = h1 . W1^T (bf16x3), A from Acur ----
    f32x4 acc[2][2];
#pragma unroll
    for (int pt = 0; pt < 2; ++pt)
#pragma unroll
      for (int ft = 0; ft < 2; ++ft) acc[pt][ft] = (f32x4){0.f, 0.f, 0.f, 0.f};
#pragma unroll
    for (int ks = 0; ks < 4; ++ks) {
      const int kc = ks * 4 + (lane >> 4);
#pragma unroll
      for (int pt = 0; pt < 2; ++pt) {
        const int arow = pt * 16 + (lane & 15);
        const int col = kc ^ (arow & 7);
        const short8v ah = *(const short8v*)(Acur + arow * 256 + col * 16);
        const short8v al =
            *(const short8v*)(Acur + 8192 + arow * 256 + col * 16);
#pragma unroll
        for (int ft = 0; ft < 2; ++ft) {
          acc[pt][ft] = mfma16x16x32bf(al, w1h[ft][ks], acc[pt][ft]);
          acc[pt][ft] = mfma16x16x32bf(ah, w1l[ft][ks], acc[pt][ft]);
          acc[pt][ft] = mfma16x16x32bf(ah, w1h[ft][ks], acc[pt][ft]);
        }
      }
    }

    // ---- issue next chunk's y loads (latency hides under H + g2) ----
    float4 a0, a1, a2, a3, n0, n1, n2, n3;
    if (j < 7) {
      const float* __restrict__ ym = y + (long)mg_next * 128 + part8 * 16;
      const float* __restrict__ yn = y + (long)(gp_next >> 3) * 128 + part8 * 16;
      a0 = *(const float4*)(ym + 0);
      a1 = *(const float4*)(ym + 4);
      a2 = *(const float4*)(ym + 8);
      a3 = *(const float4*)(ym + 12);
      n0 = *(const float4*)(yn + 0);
      n1 = *(const float4*)(yn + 4);
      n2 = *(const float4*)(yn + 8);
      n3 = *(const float4*)(yn + 12);
    }

    // ---- g1 epilogue: relu(acc+c1) -> H (packed u32, swizzled) ----
#pragma unroll
    for (int pt = 0; pt < 2; ++pt)
#pragma unroll
      for (int ft = 0; ft < 2; ++ft) {
        const int fo = wc * 32 + ft * 16 + (lane & 15);
        const int cc = fo >> 2;
        const float cb = ft ? c1v1 : c1v0;
#pragma unroll
        for (int reg = 0; reg < 4; ++reg) {
          const int p = pt * 16 + (lane >> 4) * 4 + reg;
          const float vv = relu_f(acc[pt][ft][reg] + cb);
          unsigned hh, ll;
          split3(vv, hh, ll);
          H[p * 128 + ((cc ^ (p & 7)) << 2) + (fo & 3)] = (hh << 16) | ll;
        }
      }
    __syncthreads();  // H ready

    // ---- g2: acc2 = h2 . W2^T (bf16x3), A from H ----
    f32x4 acc2[2][2];
#pragma unroll
    for (int pt = 0; pt < 2; ++pt)
#pragma unroll
      for (int ft = 0; ft < 2; ++ft) acc2[pt][ft] = (f32x4){0.f, 0.f, 0.f, 0.f};
#pragma unroll
    for (int ks = 0; ks < 4; ++ks) {
      const int cc0 = ks * 8 + (lane >> 4) * 2;
#pragma unroll
      for (int pt = 0; pt < 2; ++pt) {
        const int p = pt * 16 + (lane & 15);
        const int4 u0 = *(const int4*)&H[p * 128 + ((cc0 ^ (p & 7)) << 2)];
        const int4 u1 = *(const int4*)&H[p * 128 + (((cc0 + 1) ^ (p & 7)) << 2)];
        const unsigned uu[8] = {(unsigned)u0.x, (unsigned)u0.y, (unsigned)u0.z,
                                (unsigned)u0.w, (unsigned)u1.x, (unsigned)u1.y,
                                (unsigned)u1.z, (unsigned)u1.w};
        short8v ah, al;
#pragma unroll
        for (int e = 0; e < 8; ++e) {
          ah[e] = (short)(uu[e] >> 16);
          al[e] = (short)(uu[e] & 0xFFFFu);
        }
#pragma unroll
        for (int ft = 0; ft < 2; ++ft) {
          acc2[pt][ft] = mfma16x16x32bf(al, w2h[ft][ks], acc2[pt][ft]);
          acc2[pt][ft] = mfma16x16x32bf(ah, w2l[ft][ks], acc2[pt][ft]);
          acc2[pt][ft] = mfma16x16x32bf(ah, w2h[ft][ks], acc2[pt][ft]);
        }
      }
    }
    __syncthreads();  // H reads done (next iter may overwrite H)

    // ---- g2 epilogue: relu+max over 8 pairs/query -> OS rows j*4.. ----
    {
      const int g = lane >> 4;
#pragma unroll
      for (int pt = 0; pt < 2; ++pt)
#pragma unroll
        for (int ft = 0; ft < 2; ++ft) {
          const int fo = wc * 32 + ft * 16 + (lane & 15);
          const float cb = ft ? c2v1 : c2v0;
          const float v0 = relu_f(acc2[pt][ft][0] + cb);
          const float v1 = relu_f(acc2[pt][ft][1] + cb);
          const float v2 = relu_f(acc2[pt][ft][2] + cb);
          const float v3 = relu_f(acc2[pt][ft][3] + cb);
          float m = fmaxf(fmaxf(v0, v1), fmaxf(v2, v3));
          m = fmaxf(m, __shfl_xor(m, 16, 64));
          if ((g & 1) == 0) {
            const int qloc = pt * 2 + (g >> 1);
            OS[(j * 4 + qloc) * 128 + fo] = m;
          }
        }
    }

    // ---- pack & write A[j+1] into Anxt (loads returned during g2) ----
    if (j < 7) {
      float hv0[8] = {relu_f(a0.x - n0.x + c0a.x), relu_f(a0.y - n0.y + c0a.y),
                      relu_f(a0.z - n0.z + c0a.z), relu_f(a0.w - n0.w + c0a.w),
                      relu_f(a1.x - n1.x + c0b.x), relu_f(a1.y - n1.y + c0b.y),
                      relu_f(a1.z - n1.z + c0b.z), relu_f(a1.w - n1.w + c0b.w)};
      float hv1[8] = {relu_f(a2.x - n2.x + c0c.x), relu_f(a2.y - n2.y + c0c.y),
                      relu_f(a2.z - n2.z + c0c.z), relu_f(a2.w - n2.w + c0c.w),
                      relu_f(a3.x - n3.x + c0d.x), relu_f(a3.y - n3.y + c0d.y),
                      relu_f(a3.z - n3.z + c0d.z), relu_f(a3.w - n3.w + c0d.w)};
      PACK_WRITE_A(Anxt, hv0, part8 * 2)
      PACK_WRITE_A(Anxt, hv1, part8 * 2 + 1)
    }
    __syncthreads();  // A[j+1] ready; OS rows settled
  }

  // ---- final coalesced out-write: OS[32][128] -> out[bb][f][qseg*32..] ----
  {
    const int f = t >> 1, seg = t & 1;
    float* __restrict__ op =
        out + (long)(bb * 128 + f) * 2048 + qseg * 32 + seg * 16;
#pragma unroll
    for (int u = 0; u < 4; ++u) {
      float4 o;
      o.x = OS[(seg * 16 + u * 4 + 0) * 128 + f];
      o.y = OS[(seg * 16 + u * 4 + 1) * 128 + f];
      o.z = OS[(seg * 16 + u * 4 + 2) * 128 + f];
      o.w = OS[(seg * 16 + u * 4 + 3) * 128 + f];
      *(float4*)(op + u * 4) = o;
    }
  }
}

// ------------------------------- launch ------------------------------------
extern "C" void kernel_launch(void* const* d_in, const int* in_sizes, int n_in,
                              void* d_out, int out_size, void* d_ws,
                              size_t ws_size, hipStream_t stream) {
  (void)in_sizes; (void)n_in; (void)out_size; (void)ws_size;
  const float* x = (const float*)d_in[0];
  const float* w0 = (const float*)d_in[1];
  const float* b0 = (const float*)d_in[2];
  const float* wst = (const float*)d_in[3];
  const float* bst = (const float*)d_in[4];
  const float* g = (const float*)d_in[5];
  const float* be = (const float*)d_in[6];
  const float* bm = (const float*)d_in[7];
  const float* bv = (const float*)d_in[8];
  float* out = (float*)d_out;
  float* ws = (float*)d_ws;

  hipFuncSetAttribute((const void*)fused_kernel,
                      hipFuncAttributeMaxDynamicSharedMemorySize, 65536);

  knn_kernel<<<1056, 512, 0, stream>>>(x, w0, b0, wst, bst, g, be, bm, bv, ws);
  fused_kernel<<<512, 256, 65536, stream>>>(ws, out);
}

// Round 13
// 67.105 us; speedup vs baseline: 1.2470x; 1.1181x over previous
//
#include <hip/hip_runtime.h>

// ---------------------------------------------------------------------------
// FeatureNet: kNN(K=8) relative grouping -> [conv1x1+BN+ReLU] x3 -> max over K
// B=8, N=2048, DIM=128, fp32 in/out.
//
// knn  : R13: as R11 but all 64 per-lane distances kept in VGPRs (dv[64],
//        compile-time indices only). Phase 2 = compare+mask on registers
//        (no LDS re-reads, no recompute): -24% issue ops. VGPR ~110.
// fused: R12 (unchanged): 512 blocks x 256 thr, chunk 32 pairs, LDS 64KB,
//        W in 128 VGPRs, 2 blocks/CU co-resident.
// ---------------------------------------------------------------------------

#define EPSF 1e-5f
#define FMAXV 3.402823466e+38f

#define NB 8
#define NN 2048
#define KNBR 8
#define DIMF 128
#define NQ (NB * NN)        // 16384
#define NPAIR (NQ * KNBR)   // 131072

// ws layout. W planes in u16 units [0, 65536) == floats [0, 32768).
#define OFF16_W1H 0          // 16384 u16 (fragment order)
#define OFF16_W1L 16384
#define OFF16_W2H 32768
#define OFF16_W2L 49152
#define OFF_C0 32768         // float units
#define OFF_C1 32896
#define OFF_C2 33024
#define OFF_Y 33792          // 2097152 floats
#define OFF_IDX (OFF_Y + NQ * DIMF)   // 131072 ints

typedef __attribute__((ext_vector_type(4))) float f32x4;
typedef __attribute__((ext_vector_type(8))) short short8v;

__device__ __forceinline__ float relu_f(float a) { return fmaxf(a, 0.0f); }

// fp32 -> bf16(hi, RNE) + bf16(lo, trunc of residual)
__device__ __forceinline__ void split3(float f, unsigned& hi, unsigned& lo) {
  const unsigned u = __float_as_uint(f);
  const unsigned h = (u + 0x7FFFu + ((u >> 16) & 1u)) >> 16;
  const float hf = __uint_as_float(h << 16);
  lo = __float_as_uint(f - hf) >> 16;
  hi = h;
}

__device__ __forceinline__ f32x4 mfma16x16x32bf(short8v a, short8v b, f32x4 c) {
  return __builtin_amdgcn_mfma_f32_16x16x32_bf16(a, b, c, 0, 0, 0);
}

// ---- named-scalar selection primitives (R7 lesson: NO runtime-idx state) ----
#define KCSWAP(a, b)                  \
  {                                   \
    const float mn_ = fminf(a, b);    \
    const float mx_ = fmaxf(a, b);    \
    (a) = mn_; (b) = mx_;             \
  }

// Batcher odd-even mergesort of 8 keys (19 comparators), ascending
#define SORT8(d0, d1, d2, d3, d4, d5, d6, d7)                   \
  KCSWAP(d0, d1) KCSWAP(d2, d3) KCSWAP(d4, d5) KCSWAP(d6, d7)   \
  KCSWAP(d0, d2) KCSWAP(d1, d3) KCSWAP(d4, d6) KCSWAP(d5, d7)   \
  KCSWAP(d1, d2) KCSWAP(d5, d6)                                 \
  KCSWAP(d0, d4) KCSWAP(d1, d5) KCSWAP(d2, d6) KCSWAP(d3, d7)   \
  KCSWAP(d2, d4) KCSWAP(d3, d5)                                 \
  KCSWAP(d1, d2) KCSWAP(d3, d4) KCSWAP(d5, d6)

// 3-stage bitonic cleanup of a bitonic 8-seq in k0..k7 (sorts ascending)
#define KCLEAN8()                                               \
  KCSWAP(k0, k4) KCSWAP(k1, k5) KCSWAP(k2, k6) KCSWAP(k3, k7)   \
  KCSWAP(k0, k2) KCSWAP(k1, k3) KCSWAP(k4, k6) KCSWAP(k5, k7)   \
  KCSWAP(k0, k1) KCSWAP(k2, k3) KCSWAP(k4, k5) KCSWAP(k6, k7)

// fold sorted d0..d7 into sorted chain k0..k7 (keep low 8 of union)
#define KFOLD8(d0, d1, d2, d3, d4, d5, d6, d7)                  \
  {                                                             \
    k0 = fminf(k0, d7); k1 = fminf(k1, d6);                     \
    k2 = fminf(k2, d5); k3 = fminf(k3, d4);                     \
    k4 = fminf(k4, d3); k5 = fminf(k5, d2);                     \
    k6 = fminf(k6, d1); k7 = fminf(k7, d0);                     \
    KCLEAN8()                                                   \
  }

// Batcher merge with xor-partner's sorted 8 (both sides converge)
#define KMERGE(mv)                                              \
  {                                                             \
    const float q0_ = __shfl_xor(k0, mv, 64);                   \
    const float q1_ = __shfl_xor(k1, mv, 64);                   \
    const float q2_ = __shfl_xor(k2, mv, 64);                   \
    const float q3_ = __shfl_xor(k3, mv, 64);                   \
    const float q4_ = __shfl_xor(k4, mv, 64);                   \
    const float q5_ = __shfl_xor(k5, mv, 64);                   \
    const float q6_ = __shfl_xor(k6, mv, 64);                   \
    const float q7_ = __shfl_xor(k7, mv, 64);                   \
    k0 = fminf(k0, q7_); k1 = fminf(k1, q6_);                   \
    k2 = fminf(k2, q5_); k3 = fminf(k3, q4_);                   \
    k4 = fminf(k4, q3_); k5 = fminf(k5, q2_);                   \
    k6 = fminf(k6, q1_); k7 = fminf(k7, q0_);                   \
    KCLEAN8()                                                   \
  }

// ------------------------- knn (+y, +prep blocks) ---------------------------
// Blocks 0..1023: bb = bid>>7, queries qloc0..+16, 32 lanes/query (sg=t&31),
// slice = cands [sg*64, sg*64+64). Planes xyp/zsp float2[2080], ii=i+(i>>6)
// (lane base sg*65 -> byte stride 520 = 8 mod 128 -> 2-way-free b64 reads).
// Blocks 1024..1055: W-plane prep (fragment order) + C scalars (block 1024).
__global__ __launch_bounds__(512, 4) void knn_kernel(
    const float* __restrict__ x, const float* __restrict__ w0,
    const float* __restrict__ b0, const float* __restrict__ wstk,
    const float* __restrict__ bstk, const float* __restrict__ g,
    const float* __restrict__ be, const float* __restrict__ bm,
    const float* __restrict__ bv, float* __restrict__ ws) {
  __shared__ float2 xyp[2080];
  __shared__ float2 zsp[2080];
  const int t = threadIdx.x;
  const int bid = blockIdx.x;  // 1056

  if (bid >= 1024) {  // ---- prep path (W planes + C scalars) ----
    const int i = (bid - 1024) * 512 + t;  // 16384
    unsigned short* __restrict__ wsh = (unsigned short*)ws;
    const int fo = i >> 7, k = i & 127;
    const float s1 = g[128 + fo] / sqrtf(bv[128 + fo] + EPSF);
    const float s2 = g[256 + fo] / sqrtf(bv[256 + fo] + EPSF);
    unsigned h1, l1, h2, l2;
    split3(wstk[i] * s1, h1, l1);
    split3(wstk[16384 + i] * s2, h2, l2);
    const int dst = ((fo >> 4) * 4 + (k >> 5)) * 512 +
                    (((k >> 3) & 3) * 16 + (fo & 15)) * 8 + (k & 7);
    wsh[OFF16_W1H + dst] = (unsigned short)h1;
    wsh[OFF16_W1L + dst] = (unsigned short)l1;
    wsh[OFF16_W2H + dst] = (unsigned short)h2;
    wsh[OFF16_W2L + dst] = (unsigned short)l2;
    if (bid == 1024 && t < 128) {
      const int f = t;
      const float s0 = g[f] / sqrtf(bv[f] + EPSF);
      const float s1b = g[128 + f] / sqrtf(bv[128 + f] + EPSF);
      const float s2b = g[256 + f] / sqrtf(bv[256 + f] + EPSF);
      ws[OFF_C0 + f] = (b0[f] - bm[f]) * s0 + be[f];
      ws[OFF_C1 + f] = (bstk[f] - bm[128 + f]) * s1b + be[128 + f];
      ws[OFF_C2 + f] = (bstk[128 + f] - bm[256 + f]) * s2b + be[256 + f];
    }
    return;
  }

  const int bb = bid >> 7;
  const int qloc0 = (bid & 127) * 16;
  const float* __restrict__ xb = x + bb * 3 * NN;

  // ---- stage whole batch once ----
#pragma unroll
  for (int k = 0; k < 4; ++k) {
    const int i = t + k * 512;
    const float a0 = xb[i];
    const float a1 = xb[2048 + i];
    const float a2 = xb[4096 + i];
    const float sq = fmaf(a2, a2, fmaf(a1, a1, a0 * a0));
    const int ii = i + (i >> 6);
    xyp[ii] = make_float2(a0, a1);
    zsp[ii] = make_float2(a2, sq);
  }

  const int qi = t >> 5;   // 0..15
  const int sg = t & 31;   // slice
  const int n = qloc0 + qi;
  const int q = bb * NN + n;
  const float qx0 = xb[n], qx1 = xb[2048 + n], qx2 = xb[4096 + n];
  const float sqn = fmaf(qx2, qx2, fmaf(qx1, qx1, qx0 * qx0));

  // ---- y row: features [sg*4, sg*4+4), folded s0 inline (== old prep) ----
  {
    const int f0 = sg * 4;
    float4 yv;
    {
      const float s0 = g[f0] / sqrtf(bv[f0] + EPSF);
      yv.x = fmaf(w0[3 * f0 + 2] * s0, qx2,
                  fmaf(w0[3 * f0 + 1] * s0, qx1, (w0[3 * f0] * s0) * qx0));
    }
    {
      const float s0 = g[f0 + 1] / sqrtf(bv[f0 + 1] + EPSF);
      yv.y = fmaf(w0[3 * f0 + 5] * s0, qx2,
                  fmaf(w0[3 * f0 + 4] * s0, qx1, (w0[3 * f0 + 3] * s0) * qx0));
    }
    {
      const float s0 = g[f0 + 2] / sqrtf(bv[f0 + 2] + EPSF);
      yv.z = fmaf(w0[3 * f0 + 8] * s0, qx2,
                  fmaf(w0[3 * f0 + 7] * s0, qx1, (w0[3 * f0 + 6] * s0) * qx0));
    }
    {
      const float s0 = g[f0 + 3] / sqrtf(bv[f0 + 3] + EPSF);
      yv.w = fmaf(w0[3 * f0 + 11] * s0, qx2,
                  fmaf(w0[3 * f0 + 10] * s0, qx1, (w0[3 * f0 + 9] * s0) * qx0));
    }
    *(float4*)(ws + OFF_Y + (long)q * 128 + f0) = yv;
  }
  __syncthreads();

  const float2* __restrict__ xr = xyp + sg * 65;
  const float2* __restrict__ zr = zsp + sg * 65;

  // ---- phase 1: 8 batches of sort-8 + fold; keep ALL distances in VGPRs ----
  // dv[] accessed ONLY with compile-time indices (full unroll) -> registers.
  float dv[64];
  float k0 = FMAXV, k1 = FMAXV, k2 = FMAXV, k3 = FMAXV,
        k4 = FMAXV, k5 = FMAXV, k6 = FMAXV, k7 = FMAXV;
#pragma unroll
  for (int bt = 0; bt < 8; ++bt) {
    float d0, d1, d2, d3, d4, d5, d6, d7;
#define KD(j, dj)                                                        \
    {                                                                    \
      const float2 cxy = xr[bt * 8 + (j)];                               \
      const float2 czs = zr[bt * 8 + (j)];                               \
      const float inner =                                                \
          fmaf(qx2, czs.x, fmaf(qx1, cxy.y, qx0 * cxy.x));               \
      dj = (sqn - 2.0f * inner) + czs.y;                                 \
    }
    KD(0, d0) KD(1, d1) KD(2, d2) KD(3, d3)
    KD(4, d4) KD(5, d5) KD(6, d6) KD(7, d7)
#undef KD
    dv[bt * 8 + 0] = d0; dv[bt * 8 + 1] = d1;
    dv[bt * 8 + 2] = d2; dv[bt * 8 + 3] = d3;
    dv[bt * 8 + 4] = d4; dv[bt * 8 + 5] = d5;
    dv[bt * 8 + 6] = d6; dv[bt * 8 + 7] = d7;
    SORT8(d0, d1, d2, d3, d4, d5, d6, d7)
    KFOLD8(d0, d1, d2, d3, d4, d5, d6, d7)
  }

  // ---- cross-lane merge: 32 lanes -> exact global 8th-smallest ----
  KMERGE(1) KMERGE(2) KMERGE(4) KMERGE(8) KMERGE(16)
  const float thr = k7;

  // ---- phase 2: register compare-only rescan (same values as phase 1) ----
  unsigned am = 0, bm2 = 0;
#pragma unroll
  for (int mm = 0; mm < 32; ++mm) am |= (dv[mm] <= thr) ? (1u << mm) : 0u;
#pragma unroll
  for (int mm = 0; mm < 32; ++mm)
    bm2 |= (dv[32 + mm] <= thr) ? (1u << mm) : 0u;

  // ---- exclusive scan of per-lane counts over the 32-lane group ----
  const int cnt = __popc(am) + __popc(bm2);
  int inc = cnt, tq;
  tq = __shfl_up(inc, 1, 32); inc += (sg >= 1) ? tq : 0;
  tq = __shfl_up(inc, 2, 32); inc += (sg >= 2) ? tq : 0;
  tq = __shfl_up(inc, 4, 32); inc += (sg >= 4) ? tq : 0;
  tq = __shfl_up(inc, 8, 32); inc += (sg >= 8) ? tq : 0;
  tq = __shfl_up(inc, 16, 32); inc += (sg >= 16) ? tq : 0;
  int pos = inc - cnt;

  // ---- extraction: hits in ascending candidate index (lane-major) ----
  int* __restrict__ idxg = (int*)(ws + OFF_IDX);
  {
    unsigned w = am;
    while (w) {
      const int b = __ffs(w) - 1;
      w &= w - 1;
      if (pos < 8) idxg[q * 8 + pos] = bb * NN + sg * 64 + b;
      ++pos;
    }
    w = bm2;
    while (w) {
      const int b = __ffs(w) - 1;
      w &= w - 1;
      if (pos < 8) idxg[q * 8 + pos] = bb * NN + sg * 64 + 32 + b;
      ++pos;
    }
  }
}

// --------------------------- persistent fused ------------------------------
// R12: 512 blocks x 256 thr (4 waves, wc = w = fo-slice). Block bid:
// batch bb=bid&7, qseg=bid>>3 (0..63, 32 queries), 8 chunks of 32 pairs.
// LDS 64KB: A dbuf 2x16KB @0 (hi 8K + lo 8K each), H 16KB @32K, OS 16KB @48K.
// Two blocks co-resident per CU (VGPR ~200 -> 8 waves) -> phases interleave.
// A-plane 16B chunks swizzled col = kc ^ (row&7); H 16B chunks cc ^= (p&7).
__global__ __launch_bounds__(256, 2) void fused_kernel(float* __restrict__ ws,
                                                       float* __restrict__ out) {
  extern __shared__ char smem[];
  unsigned* __restrict__ H = (unsigned*)(smem + 32768);
  float* __restrict__ OS = (float*)(smem + 49152);

  const float* __restrict__ y = ws + OFF_Y;
  const int* __restrict__ idxg = (const int*)(ws + OFF_IDX);
  const unsigned short* __restrict__ wsu = (const unsigned short*)ws;

  const int t = threadIdx.x;
  const int lane = t & 63, w = t >> 6;
  const int wc = w;  // 4 waves = 4 fo-slices of 32
  const int bid = blockIdx.x;
  const int bb = bid & 7, qseg = bid >> 3;      // qseg 0..63
  const int chunk0 = bb * 512 + qseg * 8;       // 32-pair chunks

  // ---- W fragments -> registers (once; coalesced 1KB/wave frag loads) ----
  short8v w1h[2][4], w1l[2][4], w2h[2][4], w2l[2][4];
#pragma unroll
  for (int ft = 0; ft < 2; ++ft)
#pragma unroll
    for (int ks = 0; ks < 4; ++ks) {
      const int off = ((wc * 2 + ft) * 4 + ks) * 512 + lane * 8;
      w1h[ft][ks] = *(const short8v*)(wsu + OFF16_W1H + off);
      w1l[ft][ks] = *(const short8v*)(wsu + OFF16_W1L + off);
      w2h[ft][ks] = *(const short8v*)(wsu + OFF16_W2H + off);
      w2l[ft][ks] = *(const short8v*)(wsu + OFF16_W2L + off);
    }

  const float c1v0 = (ws + OFF_C1)[wc * 32 + (lane & 15)];
  const float c1v1 = (ws + OFF_C1)[wc * 32 + 16 + (lane & 15)];
  const float c2v0 = (ws + OFF_C2)[wc * 32 + (lane & 15)];
  const float c2v1 = (ws + OFF_C2)[wc * 32 + 16 + (lane & 15)];

  // ---- per-thread A-staging constants (row 0..31, 16 floats each) ----
  const int row = t >> 3, part8 = t & 7;
  const float* __restrict__ c0p = ws + OFF_C0 + part8 * 16;
  const float4 c0a = *(const float4*)(c0p + 0);
  const float4 c0b = *(const float4*)(c0p + 4);
  const float4 c0c = *(const float4*)(c0p + 8);
  const float4 c0d = *(const float4*)(c0p + 12);

// pack 8 floats into hi/lo int4, write swizzled (lo plane at +8192)
#define PACK_WRITE_A(base, hv, kc)                              \
  {                                                             \
    unsigned hh[8], ll[8];                                      \
    _Pragma("unroll") for (int e = 0; e < 8; ++e)               \
        split3(hv[e], hh[e], ll[e]);                            \
    int4 hp, lp;                                                \
    hp.x = (int)(hh[0] | (hh[1] << 16));                        \
    hp.y = (int)(hh[2] | (hh[3] << 16));                        \
    hp.z = (int)(hh[4] | (hh[5] << 16));                        \
    hp.w = (int)(hh[6] | (hh[7] << 16));                        \
    lp.x = (int)(ll[0] | (ll[1] << 16));                        \
    lp.y = (int)(ll[2] | (ll[3] << 16));                        \
    lp.z = (int)(ll[4] | (ll[5] << 16));                        \
    lp.w = (int)(ll[6] | (ll[7] << 16));                        \
    const int col = (kc) ^ (row & 7);                           \
    *(int4*)((base) + row * 256 + col * 16) = hp;               \
    *(int4*)((base) + 8192 + row * 256 + col * 16) = lp;        \
  }

  // ---- prologue: stage A[0] into buf0 ----
  {
    const int gp = chunk0 * 32 + row;
    const int mg = idxg[gp];
    const float* __restrict__ ym = y + (long)mg * 128 + part8 * 16;
    const float* __restrict__ yn = y + (long)(gp >> 3) * 128 + part8 * 16;
    const float4 a0 = *(const float4*)(ym + 0);
    const float4 a1 = *(const float4*)(ym + 4);
    const float4 a2 = *(const float4*)(ym + 8);
    const float4 a3 = *(const float4*)(ym + 12);
    const float4 n0 = *(const float4*)(yn + 0);
    const float4 n1 = *(const float4*)(yn + 4);
    const float4 n2 = *(const float4*)(yn + 8);
    const float4 n3 = *(const float4*)(yn + 12);
    float hv0[8] = {relu_f(a0.x - n0.x + c0a.x), relu_f(a0.y - n0.y + c0a.y),
                    relu_f(a0.z - n0.z + c0a.z), relu_f(a0.w - n0.w + c0a.w),
                    relu_f(a1.x - n1.x + c0b.x), relu_f(a1.y - n1.y + c0b.y),
                    relu_f(a1.z - n1.z + c0b.z), relu_f(a1.w - n1.w + c0b.w)};
    float hv1[8] = {relu_f(a2.x - n2.x + c0c.x), relu_f(a2.y - n2.y + c0c.y),
                    relu_f(a2.z - n2.z + c0c.z), relu_f(a2.w - n2.w + c0c.w),
                    relu_f(a3.x - n3.x + c0d.x), relu_f(a3.y - n3.y + c0d.y),
                    relu_f(a3.z - n3.z + c0d.z), relu_f(a3.w - n3.w + c0d.w)};
    PACK_WRITE_A(smem, hv0, part8 * 2)
    PACK_WRITE_A(smem, hv1, part8 * 2 + 1)
  }
  __syncthreads();

#pragma unroll 1
  for (int j = 0; j < 8; ++j) {
    char* __restrict__ Acur = smem + (j & 1) * 16384;
    char* __restrict__ Anxt = smem + ((j & 1) ^ 1) * 16384;

    int mg_next = 0, gp_next = 0;
    if (j < 7) {
      gp_next = (chunk0 + j + 1) * 32 + row;
      mg_next = idxg[gp_next];
    }

    // ---- g1: acc = h1 . W1^T (bf16x3), A from Acur ----
    f32x4 acc[2][2];
#pragma unroll
    for (int pt = 0; pt < 2; ++pt)
#pragma unroll
      for (int ft = 0; ft < 2; ++ft) acc[pt][ft] = (f32x4){0.f, 0.f, 0.f, 0.f};
#pragma unroll
    for (int ks = 0; ks < 4; ++ks) {
      const int kc = ks * 4 + (lane >> 4);
#pragma unroll
      for (int pt = 0; pt < 2; ++pt) {
        const int arow = pt * 16 + (lane & 15);
        const int col = kc ^ (arow & 7);
        const short8v ah = *(const short8v*)(Acur + arow * 256 + col * 16);
        const short8v al =
            *(const short8v*)(Acur + 8192 + arow * 256 + col * 16);
#pragma unroll
        for (int ft = 0; ft < 2; ++ft) {
          acc[pt][ft] = mfma16x16x32bf(al, w1h[ft][ks], acc[pt][ft]);
          acc[pt][ft] = mfma16x16x32bf(ah, w1l[ft][ks], acc[pt][ft]);
          acc[pt][ft] = mfma16x16x32bf(ah, w1h[ft][ks], acc[pt][ft]);
        }
      }
    }

    // ---- issue next chunk's y loads (latency hides under H + g2) ----
    float4 a0, a1, a2, a3, n0, n1, n2, n3;
    if (j < 7) {
      const float* __restrict__ ym = y + (long)mg_next * 128 + part8 * 16;
      const float* __restrict__ yn = y + (long)(gp_next >> 3) * 128 + part8 * 16;
      a0 = *(const float4*)(ym + 0);
      a1 = *(const float4*)(ym + 4);
      a2 = *(const float4*)(ym + 8);
      a3 = *(const float4*)(ym + 12);
      n0 = *(const float4*)(yn + 0);
      n1 = *(const float4*)(yn + 4);
      n2 = *(const float4*)(yn + 8);
      n3 = *(const float4*)(yn + 12);
    }

    // ---- g1 epilogue: relu(acc+c1) -> H (packed u32, swizzled) ----
#pragma unroll
    for (int pt = 0; pt < 2; ++pt)
#pragma unroll
      for (int ft = 0; ft < 2; ++ft) {
        const int fo = wc * 32 + ft * 16 + (lane & 15);
        const int cc = fo >> 2;
        const float cb = ft ? c1v1 : c1v0;
#pragma unroll
        for (int reg = 0; reg < 4; ++reg) {
          const int p = pt * 16 + (lane >> 4) * 4 + reg;
          const float vv = relu_f(acc[pt][ft][reg] + cb);
          unsigned hh, ll;
          split3(vv, hh, ll);
          H[p * 128 + ((cc ^ (p & 7)) << 2) + (fo & 3)] = (hh << 16) | ll;
        }
      }
    __syncthreads();  // H ready

    // ---- g2: acc2 = h2 . W2^T (bf16x3), A from H ----
    f32x4 acc2[2][2];
#pragma unroll
    for (int pt = 0; pt < 2; ++pt)
#pragma unroll
      for (int ft = 0; ft < 2; ++ft) acc2[pt][ft] = (f32x4){0.f, 0.f, 0.f, 0.f};
#pragma unroll
    for (int ks = 0; ks < 4; ++ks) {
      const int cc0 = ks * 8 + (lane >> 4) * 2;
#pragma unroll
      for (int pt = 0; pt < 2; ++pt) {
        const int p = pt * 16 + (lane & 15);
        const int4 u0 = *(const int4*)&H[p * 128 + ((cc0 ^ (p & 7)) << 2)];
        const int4 u1 = *(const int4*)&H[p * 128 + (((cc0 + 1) ^ (p & 7)) << 2)];
        const unsigned uu[8] = {(unsigned)u0.x, (unsigned)u0.y, (unsigned)u0.z,
                                (unsigned)u0.w, (unsigned)u1.x, (unsigned)u1.y,
                                (unsigned)u1.z, (unsigned)u1.w};
        short8v ah, al;
#pragma unroll
        for (int e = 0; e < 8; ++e) {
          ah[e] = (short)(uu[e] >> 16);
          al[e] = (short)(uu[e] & 0xFFFFu);
        }
#pragma unroll
        for (int ft = 0; ft < 2; ++ft) {
          acc2[pt][ft] = mfma16x16x32bf(al, w2h[ft][ks], acc2[pt][ft]);
          acc2[pt][ft] = mfma16x16x32bf(ah, w2l[ft][ks], acc2[pt][ft]);
          acc2[pt][ft] = mfma16x16x32bf(ah, w2h[ft][ks], acc2[pt][ft]);
        }
      }
    }
    __syncthreads();  // H reads done (next iter may overwrite H)

    // ---- g2 epilogue: relu+max over 8 pairs/query -> OS rows j*4.. ----
    {
      const int g = lane >> 4;
#pragma unroll
      for (int pt = 0; pt < 2; ++pt)
#pragma unroll
        for (int ft = 0; ft < 2; ++ft) {
          const int fo = wc * 32 + ft * 16 + (lane & 15);
          const float cb = ft ? c2v1 : c2v0;
          const float v0 = relu_f(acc2[pt][ft][0] + cb);
          const float v1 = relu_f(acc2[pt][ft][1] + cb);
          const float v2 = relu_f(acc2[pt][ft][2] + cb);
          const float v3 = relu_f(acc2[pt][ft][3] + cb);
          float m = fmaxf(fmaxf(v0, v1), fmaxf(v2, v3));
          m = fmaxf(m, __shfl_xor(m, 16, 64));
          if ((g & 1) == 0) {
            const int qloc = pt * 2 + (g >> 1);
            OS[(j * 4 + qloc) * 128 + fo] = m;
          }
        }
    }

    // ---- pack & write A[j+1] into Anxt (loads returned during g2) ----
    if (j < 7) {
      float hv0[8] = {relu_f(a0.x - n0.x + c0a.x), relu_f(a0.y - n0.y + c0a.y),
                      relu_f(a0.z - n0.z + c0a.z), relu_f(a0.w - n0.w + c0a.w),
                      relu_f(a1.x - n1.x + c0b.x), relu_f(a1.y - n1.y + c0b.y),
                      relu_f(a1.z - n1.z + c0b.z), relu_f(a1.w - n1.w + c0b.w)};
      float hv1[8] = {relu_f(a2.x - n2.x + c0c.x), relu_f(a2.y - n2.y + c0c.y),
                      relu_f(a2.z - n2.z + c0c.z), relu_f(a2.w - n2.w + c0c.w),
                      relu_f(a3.x - n3.x + c0d.x), relu_f(a3.y - n3.y + c0d.y),
                      relu_f(a3.z - n3.z + c0d.z), relu_f(a3.w - n3.w + c0d.w)};
      PACK_WRITE_A(Anxt, hv0, part8 * 2)
      PACK_WRITE_A(Anxt, hv1, part8 * 2 + 1)
    }
    __syncthreads();  // A[j+1] ready; OS rows settled
  }

  // ---- final coalesced out-write: OS[32][128] -> out[bb][f][qseg*32..] ----
  {
    const int f = t >> 1, seg = t & 1;
    float* __restrict__ op =
        out + (long)(bb * 128 + f) * 2048 + qseg * 32 + seg * 16;
#pragma unroll
    for (int u = 0; u < 4; ++u) {
      float4 o;
      o.x = OS[(seg * 16 + u * 4 + 0) * 128 + f];
      o.y = OS[(seg * 16 + u * 4 + 1) * 128 + f];
      o.z = OS[(seg * 16 + u * 4 + 2) * 128 + f];
      o.w = OS[(seg * 16 + u * 4 + 3) * 128 + f];
      *(float4*)(op + u * 4) = o;
    }
  }
}

// ------------------------------- launch ------------------------------------
extern "C" void kernel_launch(void* const* d_in, const int* in_sizes, int n_in,
                              void* d_out, int out_size, void* d_ws,
                              size_t ws_size, hipStream_t stream) {
  (void)in_sizes; (void)n_in; (void)out_size; (void)ws_size;
  const float* x = (const float*)d_in[0];
  const float* w0 = (const float*)d_in[1];
  const float* b0 = (const float*)d_in[2];
  const float* wst = (const float*)d_in[3];
  const float* bst = (const float*)d_in[4];
  const float* g = (const float*)d_in[5];
  const float* be = (const float*)d_in[6];
  const float* bm = (const float*)d_in[7];
  const float* bv = (const float*)d_in[8];
  float* out = (float*)d_out;
  float* ws = (float*)d_ws;

  hipFuncSetAttribute((const void*)fused_kernel,
                      hipFuncAttributeMaxDynamicSharedMemorySize, 65536);

  knn_kernel<<<1056, 512, 0, stream>>>(x, w0, b0, wst, bst, g, be, bm, bv, ws);
  fused_kernel<<<512, 256, 65536, stream>>>(ws, out);
}

// Round 14
// 60.897 us; speedup vs baseline: 1.3741x; 1.1019x over previous
//
#include <hip/hip_runtime.h>

// ---------------------------------------------------------------------------
// FeatureNet: kNN(K=8) relative grouping -> [conv1x1+BN+ReLU] x3 -> max over K
// B=8, N=2048, DIM=128, fp32 in/out.
//
// knn  : R13 structure (dv[64] register rescan), minus the y computation
//        (y no longer exists). Prep blocks: W planes + C1/C2 + W0F4
//        (s0-folded w0 triple + c0 packed in .w).
// fused: R14: A-stage computes h1 = relu(W0f.(x_m - x_n) + c0) DIRECTLY from
//        x (24KB/batch, L1-resident) -- no y array, no L2 y-gather. W0F4 in
//        LDS (2KB, perm'd conflict-free). s_setprio(1) around MFMA loops
//        (2 independent blocks/CU = role diversity -> T5 applies).
// ---------------------------------------------------------------------------

#define EPSF 1e-5f
#define FMAXV 3.402823466e+38f

#define NB 8
#define NN 2048
#define KNBR 8
#define DIMF 128
#define NQ (NB * NN)        // 16384
#define NPAIR (NQ * KNBR)   // 131072

// ws layout. W planes in u16 units [0, 65536) == floats [0, 32768).
#define OFF16_W1H 0          // 16384 u16 (fragment order)
#define OFF16_W1L 16384
#define OFF16_W2H 32768
#define OFF16_W2L 49152
#define OFF_C1 32896         // float units
#define OFF_C2 33024
#define OFF_W0F 33152        // 512 floats: [f][4] = (w0*s0 x3, c0)
#define OFF_IDX 33792        // 131072 ints

typedef __attribute__((ext_vector_type(4))) float f32x4;
typedef __attribute__((ext_vector_type(8))) short short8v;

__device__ __forceinline__ float relu_f(float a) { return fmaxf(a, 0.0f); }

// fp32 -> bf16(hi, RNE) + bf16(lo, trunc of residual)
__device__ __forceinline__ void split3(float f, unsigned& hi, unsigned& lo) {
  const unsigned u = __float_as_uint(f);
  const unsigned h = (u + 0x7FFFu + ((u >> 16) & 1u)) >> 16;
  const float hf = __uint_as_float(h << 16);
  lo = __float_as_uint(f - hf) >> 16;
  hi = h;
}

__device__ __forceinline__ f32x4 mfma16x16x32bf(short8v a, short8v b, f32x4 c) {
  return __builtin_amdgcn_mfma_f32_16x16x32_bf16(a, b, c, 0, 0, 0);
}

// ---- named-scalar selection primitives (R7 lesson: NO runtime-idx state) ----
#define KCSWAP(a, b)                  \
  {                                   \
    const float mn_ = fminf(a, b);    \
    const float mx_ = fmaxf(a, b);    \
    (a) = mn_; (b) = mx_;             \
  }

// Batcher odd-even mergesort of 8 keys (19 comparators), ascending
#define SORT8(d0, d1, d2, d3, d4, d5, d6, d7)                   \
  KCSWAP(d0, d1) KCSWAP(d2, d3) KCSWAP(d4, d5) KCSWAP(d6, d7)   \
  KCSWAP(d0, d2) KCSWAP(d1, d3) KCSWAP(d4, d6) KCSWAP(d5, d7)   \
  KCSWAP(d1, d2) KCSWAP(d5, d6)                                 \
  KCSWAP(d0, d4) KCSWAP(d1, d5) KCSWAP(d2, d6) KCSWAP(d3, d7)   \
  KCSWAP(d2, d4) KCSWAP(d3, d5)                                 \
  KCSWAP(d1, d2) KCSWAP(d3, d4) KCSWAP(d5, d6)

// 3-stage bitonic cleanup of a bitonic 8-seq in k0..k7 (sorts ascending)
#define KCLEAN8()                                               \
  KCSWAP(k0, k4) KCSWAP(k1, k5) KCSWAP(k2, k6) KCSWAP(k3, k7)   \
  KCSWAP(k0, k2) KCSWAP(k1, k3) KCSWAP(k4, k6) KCSWAP(k5, k7)   \
  KCSWAP(k0, k1) KCSWAP(k2, k3) KCSWAP(k4, k5) KCSWAP(k6, k7)

// fold sorted d0..d7 into sorted chain k0..k7 (keep low 8 of union)
#define KFOLD8(d0, d1, d2, d3, d4, d5, d6, d7)                  \
  {                                                             \
    k0 = fminf(k0, d7); k1 = fminf(k1, d6);                     \
    k2 = fminf(k2, d5); k3 = fminf(k3, d4);                     \
    k4 = fminf(k4, d3); k5 = fminf(k5, d2);                     \
    k6 = fminf(k6, d1); k7 = fminf(k7, d0);                     \
    KCLEAN8()                                                   \
  }

// Batcher merge with xor-partner's sorted 8 (both sides converge)
#define KMERGE(mv)                                              \
  {                                                             \
    const float q0_ = __shfl_xor(k0, mv, 64);                   \
    const float q1_ = __shfl_xor(k1, mv, 64);                   \
    const float q2_ = __shfl_xor(k2, mv, 64);                   \
    const float q3_ = __shfl_xor(k3, mv, 64);                   \
    const float q4_ = __shfl_xor(k4, mv, 64);                   \
    const float q5_ = __shfl_xor(k5, mv, 64);                   \
    const float q6_ = __shfl_xor(k6, mv, 64);                   \
    const float q7_ = __shfl_xor(k7, mv, 64);                   \
    k0 = fminf(k0, q7_); k1 = fminf(k1, q6_);                   \
    k2 = fminf(k2, q5_); k3 = fminf(k3, q4_);                   \
    k4 = fminf(k4, q3_); k5 = fminf(k5, q2_);                   \
    k6 = fminf(k6, q1_); k7 = fminf(k7, q0_);                   \
    KCLEAN8()                                                   \
  }

// ------------------------- knn (+prep blocks) -------------------------------
// Blocks 0..1023: bb = bid>>7, queries qloc0..+16, 32 lanes/query (sg=t&31),
// slice = cands [sg*64, sg*64+64). Planes xyp/zsp float2[2080], ii=i+(i>>6)
// (lane base sg*65 -> byte stride 520 = 8 mod 128 -> 2-way-free b64 reads).
// Blocks 1024..1055: W-plane prep (fragment order); block 1024 also C1/C2
// and W0F4 = (w0*s0 triple, c0).
__global__ __launch_bounds__(512, 4) void knn_kernel(
    const float* __restrict__ x, const float* __restrict__ w0,
    const float* __restrict__ b0, const float* __restrict__ wstk,
    const float* __restrict__ bstk, const float* __restrict__ g,
    const float* __restrict__ be, const float* __restrict__ bm,
    const float* __restrict__ bv, float* __restrict__ ws) {
  __shared__ float2 xyp[2080];
  __shared__ float2 zsp[2080];
  const int t = threadIdx.x;
  const int bid = blockIdx.x;  // 1056

  if (bid >= 1024) {  // ---- prep path ----
    const int i = (bid - 1024) * 512 + t;  // 16384
    unsigned short* __restrict__ wsh = (unsigned short*)ws;
    const int fo = i >> 7, k = i & 127;
    const float s1 = g[128 + fo] / sqrtf(bv[128 + fo] + EPSF);
    const float s2 = g[256 + fo] / sqrtf(bv[256 + fo] + EPSF);
    unsigned h1, l1, h2, l2;
    split3(wstk[i] * s1, h1, l1);
    split3(wstk[16384 + i] * s2, h2, l2);
    const int dst = ((fo >> 4) * 4 + (k >> 5)) * 512 +
                    (((k >> 3) & 3) * 16 + (fo & 15)) * 8 + (k & 7);
    wsh[OFF16_W1H + dst] = (unsigned short)h1;
    wsh[OFF16_W1L + dst] = (unsigned short)l1;
    wsh[OFF16_W2H + dst] = (unsigned short)h2;
    wsh[OFF16_W2L + dst] = (unsigned short)l2;
    if (bid == 1024 && t < 128) {
      const int f = t;
      const float s0 = g[f] / sqrtf(bv[f] + EPSF);
      const float s1b = g[128 + f] / sqrtf(bv[128 + f] + EPSF);
      const float s2b = g[256 + f] / sqrtf(bv[256 + f] + EPSF);
      ws[OFF_C1 + f] = (bstk[f] - bm[128 + f]) * s1b + be[128 + f];
      ws[OFF_C2 + f] = (bstk[128 + f] - bm[256 + f]) * s2b + be[256 + f];
      float4 wv;
      wv.x = w0[3 * f + 0] * s0;
      wv.y = w0[3 * f + 1] * s0;
      wv.z = w0[3 * f + 2] * s0;
      wv.w = (b0[f] - bm[f]) * s0 + be[f];  // c0
      *((float4*)(ws + OFF_W0F) + f) = wv;
    }
    return;
  }

  const int bb = bid >> 7;
  const int qloc0 = (bid & 127) * 16;
  const float* __restrict__ xb = x + bb * 3 * NN;

  // ---- stage whole batch once ----
#pragma unroll
  for (int k = 0; k < 4; ++k) {
    const int i = t + k * 512;
    const float a0 = xb[i];
    const float a1 = xb[2048 + i];
    const float a2 = xb[4096 + i];
    const float sq = fmaf(a2, a2, fmaf(a1, a1, a0 * a0));
    const int ii = i + (i >> 6);
    xyp[ii] = make_float2(a0, a1);
    zsp[ii] = make_float2(a2, sq);
  }

  const int qi = t >> 5;   // 0..15
  const int sg = t & 31;   // slice
  const int n = qloc0 + qi;
  const int q = bb * NN + n;
  const float qx0 = xb[n], qx1 = xb[2048 + n], qx2 = xb[4096 + n];
  const float sqn = fmaf(qx2, qx2, fmaf(qx1, qx1, qx0 * qx0));
  __syncthreads();

  const float2* __restrict__ xr = xyp + sg * 65;
  const float2* __restrict__ zr = zsp + sg * 65;

  // ---- phase 1: 8 batches of sort-8 + fold; keep ALL distances in VGPRs ----
  float dv[64];
  float k0 = FMAXV, k1 = FMAXV, k2 = FMAXV, k3 = FMAXV,
        k4 = FMAXV, k5 = FMAXV, k6 = FMAXV, k7 = FMAXV;
#pragma unroll
  for (int bt = 0; bt < 8; ++bt) {
    float d0, d1, d2, d3, d4, d5, d6, d7;
#define KD(j, dj)                                                        \
    {                                                                    \
      const float2 cxy = xr[bt * 8 + (j)];                               \
      const float2 czs = zr[bt * 8 + (j)];                               \
      const float inner =                                                \
          fmaf(qx2, czs.x, fmaf(qx1, cxy.y, qx0 * cxy.x));               \
      dj = (sqn - 2.0f * inner) + czs.y;                                 \
    }
    KD(0, d0) KD(1, d1) KD(2, d2) KD(3, d3)
    KD(4, d4) KD(5, d5) KD(6, d6) KD(7, d7)
#undef KD
    dv[bt * 8 + 0] = d0; dv[bt * 8 + 1] = d1;
    dv[bt * 8 + 2] = d2; dv[bt * 8 + 3] = d3;
    dv[bt * 8 + 4] = d4; dv[bt * 8 + 5] = d5;
    dv[bt * 8 + 6] = d6; dv[bt * 8 + 7] = d7;
    SORT8(d0, d1, d2, d3, d4, d5, d6, d7)
    KFOLD8(d0, d1, d2, d3, d4, d5, d6, d7)
  }

  // ---- cross-lane merge: 32 lanes -> exact global 8th-smallest ----
  KMERGE(1) KMERGE(2) KMERGE(4) KMERGE(8) KMERGE(16)
  const float thr = k7;

  // ---- phase 2: register compare-only rescan ----
  unsigned am = 0, bm2 = 0;
#pragma unroll
  for (int mm = 0; mm < 32; ++mm) am |= (dv[mm] <= thr) ? (1u << mm) : 0u;
#pragma unroll
  for (int mm = 0; mm < 32; ++mm)
    bm2 |= (dv[32 + mm] <= thr) ? (1u << mm) : 0u;

  // ---- exclusive scan of per-lane counts over the 32-lane group ----
  const int cnt = __popc(am) + __popc(bm2);
  int inc = cnt, tq;
  tq = __shfl_up(inc, 1, 32); inc += (sg >= 1) ? tq : 0;
  tq = __shfl_up(inc, 2, 32); inc += (sg >= 2) ? tq : 0;
  tq = __shfl_up(inc, 4, 32); inc += (sg >= 4) ? tq : 0;
  tq = __shfl_up(inc, 8, 32); inc += (sg >= 8) ? tq : 0;
  tq = __shfl_up(inc, 16, 32); inc += (sg >= 16) ? tq : 0;
  int pos = inc - cnt;

  // ---- extraction: hits in ascending candidate index (lane-major) ----
  int* __restrict__ idxg = (int*)(ws + OFF_IDX);
  {
    unsigned w = am;
    while (w) {
      const int b = __ffs(w) - 1;
      w &= w - 1;
      if (pos < 8) idxg[q * 8 + pos] = bb * NN + sg * 64 + b;
      ++pos;
    }
    w = bm2;
    while (w) {
      const int b = __ffs(w) - 1;
      w &= w - 1;
      if (pos < 8) idxg[q * 8 + pos] = bb * NN + sg * 64 + 32 + b;
      ++pos;
    }
  }
}

// --------------------------- persistent fused ------------------------------
// R14: 512 blocks x 256 thr (4 waves, wc = w). Block: batch bb=bid&7,
// qseg=bid>>3 (32 queries), 8 chunks of 32 pairs. LDS 66KB: A dbuf 2x16KB @0,
// H 16KB @32K, OS 16KB @48K, W0L float4[128] @64K (perm'd conflict-free).
// h1 computed from x directly (L1-hot); no y array anywhere.
__global__ __launch_bounds__(256, 2) void fused_kernel(
    const float* __restrict__ x, float* __restrict__ ws,
    float* __restrict__ out) {
  extern __shared__ char smem[];
  unsigned* __restrict__ H = (unsigned*)(smem + 32768);
  float* __restrict__ OS = (float*)(smem + 49152);
  float4* __restrict__ W0L = (float4*)(smem + 65536);

  const int* __restrict__ idxg = (const int*)(ws + OFF_IDX);
  const unsigned short* __restrict__ wsu = (const unsigned short*)ws;

  const int t = threadIdx.x;
  const int lane = t & 63, w = t >> 6;
  const int wc = w;
  const int bid = blockIdx.x;
  const int bb = bid & 7, qseg = bid >> 3;
  const int chunk0 = bb * 512 + qseg * 8;
  const float* __restrict__ xb = x + bb * 3 * NN;

  // ---- W0F4 -> LDS, perm(f) = ((f&7)<<4)|(f>>3) (bank-spread reads) ----
  if (t < 128) {
    const float4 wv = *((const float4*)(ws + OFF_W0F) + t);
    W0L[((t & 7) << 4) | (t >> 3)] = wv;
  }

  // ---- W fragments -> registers (once; coalesced 1KB/wave frag loads) ----
  short8v w1h[2][4], w1l[2][4], w2h[2][4], w2l[2][4];
#pragma unroll
  for (int ft = 0; ft < 2; ++ft)
#pragma unroll
    for (int ks = 0; ks < 4; ++ks) {
      const int off = ((wc * 2 + ft) * 4 + ks) * 512 + lane * 8;
      w1h[ft][ks] = *(const short8v*)(wsu + OFF16_W1H + off);
      w1l[ft][ks] = *(const short8v*)(wsu + OFF16_W1L + off);
      w2h[ft][ks] = *(const short8v*)(wsu + OFF16_W2H + off);
      w2l[ft][ks] = *(const short8v*)(wsu + OFF16_W2L + off);
    }

  const float c1v0 = (ws + OFF_C1)[wc * 32 + (lane & 15)];
  const float c1v1 = (ws + OFF_C1)[wc * 32 + 16 + (lane & 15)];
  const float c2v0 = (ws + OFF_C2)[wc * 32 + (lane & 15)];
  const float c2v1 = (ws + OFF_C2)[wc * 32 + 16 + (lane & 15)];

  const int row = t >> 3, part8 = t & 7;
  __syncthreads();  // W0L ready

// pack 8 floats into hi/lo int4, write swizzled (lo plane at +8192)
#define PACK_WRITE_A(base, hv, kc)                              \
  {                                                             \
    unsigned hh[8], ll[8];                                      \
    _Pragma("unroll") for (int e = 0; e < 8; ++e)               \
        split3(hv[e], hh[e], ll[e]);                            \
    int4 hp, lp;                                                \
    hp.x = (int)(hh[0] | (hh[1] << 16));                        \
    hp.y = (int)(hh[2] | (hh[3] << 16));                        \
    hp.z = (int)(hh[4] | (hh[5] << 16));                        \
    hp.w = (int)(hh[6] | (hh[7] << 16));                        \
    lp.x = (int)(ll[0] | (ll[1] << 16));                        \
    lp.y = (int)(ll[2] | (ll[3] << 16));                        \
    lp.z = (int)(ll[4] | (ll[5] << 16));                        \
    lp.w = (int)(ll[6] | (ll[7] << 16));                        \
    const int col = (kc) ^ (row & 7);                           \
    *(int4*)((base) + row * 256 + col * 16) = hp;               \
    *(int4*)((base) + 8192 + row * 256 + col * 16) = lp;        \
  }

// compute h1 (16 feats) from rel coords + W0L, pack into A plane
#define STAGE_A(base, R0, R1, R2)                               \
  {                                                             \
    float hv0[8], hv1[8];                                       \
    _Pragma("unroll") for (int e = 0; e < 8; ++e) {             \
      const float4 wa = W0L[e * 16 + part8 * 2];                \
      const float4 wb = W0L[e * 16 + part8 * 2 + 1];            \
      hv0[e] = relu_f(                                          \
          fmaf(wa.z, R2, fmaf(wa.y, R1, fmaf(wa.x, R0, wa.w))));\
      hv1[e] = relu_f(                                          \
          fmaf(wb.z, R2, fmaf(wb.y, R1, fmaf(wb.x, R0, wb.w))));\
    }                                                           \
    PACK_WRITE_A(base, hv0, part8 * 2)                          \
    PACK_WRITE_A(base, hv1, part8 * 2 + 1)                      \
  }

  // ---- prologue: stage A[0] into buf0 ----
  {
    const int gp = chunk0 * 32 + row;
    const int mg = idxg[gp];
    const int mloc = mg & 2047, nloc = (gp >> 3) & 2047;
    const float r0 = xb[mloc] - xb[nloc];
    const float r1 = xb[2048 + mloc] - xb[2048 + nloc];
    const float r2 = xb[4096 + mloc] - xb[4096 + nloc];
    STAGE_A(smem, r0, r1, r2)
  }
  __syncthreads();

#pragma unroll 1
  for (int j = 0; j < 8; ++j) {
    char* __restrict__ Acur = smem + (j & 1) * 16384;
    char* __restrict__ Anxt = smem + ((j & 1) ^ 1) * 16384;

    int mg_next = 0, gp_next = 0;
    if (j < 7) {
      gp_next = (chunk0 + j + 1) * 32 + row;
      mg_next = idxg[gp_next];
    }

    // ---- g1: acc = h1 . W1^T (bf16x3), A from Acur ----
    f32x4 acc[2][2];
#pragma unroll
    for (int pt = 0; pt < 2; ++pt)
#pragma unroll
      for (int ft = 0; ft < 2; ++ft) acc[pt][ft] = (f32x4){0.f, 0.f, 0.f, 0.f};
    __builtin_amdgcn_s_setprio(1);
#pragma unroll
    for (int ks = 0; ks < 4; ++ks) {
      const int kc = ks * 4 + (lane >> 4);
#pragma unroll
      for (int pt = 0; pt < 2; ++pt) {
        const int arow = pt * 16 + (lane & 15);
        const int col = kc ^ (arow & 7);
        const short8v ah = *(const short8v*)(Acur + arow * 256 + col * 16);
        const short8v al =
            *(const short8v*)(Acur + 8192 + arow * 256 + col * 16);
#pragma unroll
        for (int ft = 0; ft < 2; ++ft) {
          acc[pt][ft] = mfma16x16x32bf(al, w1h[ft][ks], acc[pt][ft]);
          acc[pt][ft] = mfma16x16x32bf(ah, w1l[ft][ks], acc[pt][ft]);
          acc[pt][ft] = mfma16x16x32bf(ah, w1h[ft][ks], acc[pt][ft]);
        }
      }
    }
    __builtin_amdgcn_s_setprio(0);

    // ---- issue next chunk's x loads (L1-hot; hides under H + g2) ----
    float r0n = 0.f, r1n = 0.f, r2n = 0.f;
    if (j < 7) {
      const int mloc = mg_next & 2047, nloc = (gp_next >> 3) & 2047;
      r0n = xb[mloc] - xb[nloc];
      r1n = xb[2048 + mloc] - xb[2048 + nloc];
      r2n = xb[4096 + mloc] - xb[4096 + nloc];
    }

    // ---- g1 epilogue: relu(acc+c1) -> H (packed u32, swizzled) ----
#pragma unroll
    for (int pt = 0; pt < 2; ++pt)
#pragma unroll
      for (int ft = 0; ft < 2; ++ft) {
        const int fo = wc * 32 + ft * 16 + (lane & 15);
        const int cc = fo >> 2;
        const float cb = ft ? c1v1 : c1v0;
#pragma unroll
        for (int reg = 0; reg < 4; ++reg) {
          const int p = pt * 16 + (lane >> 4) * 4 + reg;
          const float vv = relu_f(acc[pt][ft][reg] + cb);
          unsigned hh, ll;
          split3(vv, hh, ll);
          H[p * 128 + ((cc ^ (p & 7)) << 2) + (fo & 3)] = (hh << 16) | ll;
        }
      }
    __syncthreads();  // H ready

    // ---- g2: acc2 = h2 . W2^T (bf16x3), A from H ----
    f32x4 acc2[2][2];
#pragma unroll
    for (int pt = 0; pt < 2; ++pt)
#pragma unroll
      for (int ft = 0; ft < 2; ++ft) acc2[pt][ft] = (f32x4){0.f, 0.f, 0.f, 0.f};
    __builtin_amdgcn_s_setprio(1);
#pragma unroll
    for (int ks = 0; ks < 4; ++ks) {
      const int cc0 = ks * 8 + (lane >> 4) * 2;
#pragma unroll
      for (int pt = 0; pt < 2; ++pt) {
        const int p = pt * 16 + (lane & 15);
        const int4 u0 = *(const int4*)&H[p * 128 + ((cc0 ^ (p & 7)) << 2)];
        const int4 u1 = *(const int4*)&H[p * 128 + (((cc0 + 1) ^ (p & 7)) << 2)];
        const unsigned uu[8] = {(unsigned)u0.x, (unsigned)u0.y, (unsigned)u0.z,
                                (unsigned)u0.w, (unsigned)u1.x, (unsigned)u1.y,
                                (unsigned)u1.z, (unsigned)u1.w};
        short8v ah, al;
#pragma unroll
        for (int e = 0; e < 8; ++e) {
          ah[e] = (short)(uu[e] >> 16);
          al[e] = (short)(uu[e] & 0xFFFFu);
        }
#pragma unroll
        for (int ft = 0; ft < 2; ++ft) {
          acc2[pt][ft] = mfma16x16x32bf(al, w2h[ft][ks], acc2[pt][ft]);
          acc2[pt][ft] = mfma16x16x32bf(ah, w2l[ft][ks], acc2[pt][ft]);
          acc2[pt][ft] = mfma16x16x32bf(ah, w2h[ft][ks], acc2[pt][ft]);
        }
      }
    }
    __builtin_amdgcn_s_setprio(0);
    __syncthreads();  // H reads done (next iter may overwrite H)

    // ---- g2 epilogue: relu+max over 8 pairs/query -> OS rows j*4.. ----
    {
      const int g = lane >> 4;
#pragma unroll
      for (int pt = 0; pt < 2; ++pt)
#pragma unroll
        for (int ft = 0; ft < 2; ++ft) {
          const int fo = wc * 32 + ft * 16 + (lane & 15);
          const float cb = ft ? c2v1 : c2v0;
          const float v0 = relu_f(acc2[pt][ft][0] + cb);
          const float v1 = relu_f(acc2[pt][ft][1] + cb);
          const float v2 = relu_f(acc2[pt][ft][2] + cb);
          const float v3 = relu_f(acc2[pt][ft][3] + cb);
          float m = fmaxf(fmaxf(v0, v1), fmaxf(v2, v3));
          m = fmaxf(m, __shfl_xor(m, 16, 64));
          if ((g & 1) == 0) {
            const int qloc = pt * 2 + (g >> 1);
            OS[(j * 4 + qloc) * 128 + fo] = m;
          }
        }
    }

    // ---- compute & write A[j+1] into Anxt ----
    if (j < 7) {
      STAGE_A(Anxt, r0n, r1n, r2n)
    }
    __syncthreads();  // A[j+1] ready; OS rows settled
  }

  // ---- final coalesced out-write: OS[32][128] -> out[bb][f][qseg*32..] ----
  {
    const int f = t >> 1, seg = t & 1;
    float* __restrict__ op =
        out + (long)(bb * 128 + f) * 2048 + qseg * 32 + seg * 16;
#pragma unroll
    for (int u = 0; u < 4; ++u) {
      float4 o;
      o.x = OS[(seg * 16 + u * 4 + 0) * 128 + f];
      o.y = OS[(seg * 16 + u * 4 + 1) * 128 + f];
      o.z = OS[(seg * 16 + u * 4 + 2) * 128 + f];
      o.w = OS[(seg * 16 + u * 4 + 3) * 128 + f];
      *(float4*)(op + u * 4) = o;
    }
  }
}

// ------------------------------- launch ------------------------------------
extern "C" void kernel_launch(void* const* d_in, const int* in_sizes, int n_in,
                              void* d_out, int out_size, void* d_ws,
                              size_t ws_size, hipStream_t stream) {
  (void)in_sizes; (void)n_in; (void)out_size; (void)ws_size;
  const float* x = (const float*)d_in[0];
  const float* w0 = (const float*)d_in[1];
  const float* b0 = (const float*)d_in[2];
  const float* wst = (const float*)d_in[3];
  const float* bst = (const float*)d_in[4];
  const float* g = (const float*)d_in[5];
  const float* be = (const float*)d_in[6];
  const float* bm = (const float*)d_in[7];
  const float* bv = (const float*)d_in[8];
  float* out = (float*)d_out;
  float* ws = (float*)d_ws;

  hipFuncSetAttribute((const void*)fused_kernel,
                      hipFuncAttributeMaxDynamicSharedMemorySize, 69632);

  knn_kernel<<<1056, 512, 0, stream>>>(x, w0, b0, wst, bst, g, be, bm, bv, ws);
  fused_kernel<<<512, 256, 67584, stream>>>(x, ws, out);
}

// Round 15
// 59.437 us; speedup vs baseline: 1.4079x; 1.0246x over previous
//
#include <hip/hip_runtime.h>

// ---------------------------------------------------------------------------
// FeatureNet: kNN(K=8) relative grouping -> [conv1x1+BN+ReLU] x3 -> max over K
// B=8, N=2048, DIM=128, fp32 in/out.
//
// knn  : R14 (unchanged): 1056 blocks x 512 thr; batch staged once; sort8+fold
//        phase1; 5 merge rounds -> exact threshold; register-mask rescan ->
//        idx[q][8]; prep blocks 1024+ (W planes + C1/C2 + W0F4).
// fused: R15: ONE barrier per chunk (was 3). A and H both double-buffered;
//        segment = [idx-prefetch j+2 | g2(H[j]) | OS | g1(A[j+1]) |
//        Hwrite(H[j+1]) | STAGE_A(A[j], j+2)] barrier. OS = 16 queries (8KB),
//        flushed at j=3 and j=7. LDS 74KB -> 2 blocks/CU. setprio around the
//        fused 96-MFMA cluster.
// ---------------------------------------------------------------------------

#define EPSF 1e-5f
#define FMAXV 3.402823466e+38f

#define NB 8
#define NN 2048
#define KNBR 8
#define DIMF 128
#define NQ (NB * NN)        // 16384
#define NPAIR (NQ * KNBR)   // 131072

// ws layout. W planes in u16 units [0, 65536) == floats [0, 32768).
#define OFF16_W1H 0          // 16384 u16 (fragment order)
#define OFF16_W1L 16384
#define OFF16_W2H 32768
#define OFF16_W2L 49152
#define OFF_C1 32896         // float units
#define OFF_C2 33024
#define OFF_W0F 33152        // 512 floats: [f][4] = (w0*s0 x3, c0)
#define OFF_IDX 33792        // 131072 ints

typedef __attribute__((ext_vector_type(4))) float f32x4;
typedef __attribute__((ext_vector_type(8))) short short8v;

__device__ __forceinline__ float relu_f(float a) { return fmaxf(a, 0.0f); }

// fp32 -> bf16(hi, RNE) + bf16(lo, trunc of residual)
__device__ __forceinline__ void split3(float f, unsigned& hi, unsigned& lo) {
  const unsigned u = __float_as_uint(f);
  const unsigned h = (u + 0x7FFFu + ((u >> 16) & 1u)) >> 16;
  const float hf = __uint_as_float(h << 16);
  lo = __float_as_uint(f - hf) >> 16;
  hi = h;
}

__device__ __forceinline__ f32x4 mfma16x16x32bf(short8v a, short8v b, f32x4 c) {
  return __builtin_amdgcn_mfma_f32_16x16x32_bf16(a, b, c, 0, 0, 0);
}

// ---- named-scalar selection primitives (R7 lesson: NO runtime-idx state) ----
#define KCSWAP(a, b)                  \
  {                                   \
    const float mn_ = fminf(a, b);    \
    const float mx_ = fmaxf(a, b);    \
    (a) = mn_; (b) = mx_;             \
  }

// Batcher odd-even mergesort of 8 keys (19 comparators), ascending
#define SORT8(d0, d1, d2, d3, d4, d5, d6, d7)                   \
  KCSWAP(d0, d1) KCSWAP(d2, d3) KCSWAP(d4, d5) KCSWAP(d6, d7)   \
  KCSWAP(d0, d2) KCSWAP(d1, d3) KCSWAP(d4, d6) KCSWAP(d5, d7)   \
  KCSWAP(d1, d2) KCSWAP(d5, d6)                                 \
  KCSWAP(d0, d4) KCSWAP(d1, d5) KCSWAP(d2, d6) KCSWAP(d3, d7)   \
  KCSWAP(d2, d4) KCSWAP(d3, d5)                                 \
  KCSWAP(d1, d2) KCSWAP(d3, d4) KCSWAP(d5, d6)

// 3-stage bitonic cleanup of a bitonic 8-seq in k0..k7 (sorts ascending)
#define KCLEAN8()                                               \
  KCSWAP(k0, k4) KCSWAP(k1, k5) KCSWAP(k2, k6) KCSWAP(k3, k7)   \
  KCSWAP(k0, k2) KCSWAP(k1, k3) KCSWAP(k4, k6) KCSWAP(k5, k7)   \
  KCSWAP(k0, k1) KCSWAP(k2, k3) KCSWAP(k4, k5) KCSWAP(k6, k7)

// fold sorted d0..d7 into sorted chain k0..k7 (keep low 8 of union)
#define KFOLD8(d0, d1, d2, d3, d4, d5, d6, d7)                  \
  {                                                             \
    k0 = fminf(k0, d7); k1 = fminf(k1, d6);                     \
    k2 = fminf(k2, d5); k3 = fminf(k3, d4);                     \
    k4 = fminf(k4, d3); k5 = fminf(k5, d2);                     \
    k6 = fminf(k6, d1); k7 = fminf(k7, d0);                     \
    KCLEAN8()                                                   \
  }

// Batcher merge with xor-partner's sorted 8 (both sides converge)
#define KMERGE(mv)                                              \
  {                                                             \
    const float q0_ = __shfl_xor(k0, mv, 64);                   \
    const float q1_ = __shfl_xor(k1, mv, 64);                   \
    const float q2_ = __shfl_xor(k2, mv, 64);                   \
    const float q3_ = __shfl_xor(k3, mv, 64);                   \
    const float q4_ = __shfl_xor(k4, mv, 64);                   \
    const float q5_ = __shfl_xor(k5, mv, 64);                   \
    const float q6_ = __shfl_xor(k6, mv, 64);                   \
    const float q7_ = __shfl_xor(k7, mv, 64);                   \
    k0 = fminf(k0, q7_); k1 = fminf(k1, q6_);                   \
    k2 = fminf(k2, q5_); k3 = fminf(k3, q4_);                   \
    k4 = fminf(k4, q3_); k5 = fminf(k5, q2_);                   \
    k6 = fminf(k6, q1_); k7 = fminf(k7, q0_);                   \
    KCLEAN8()                                                   \
  }

// ------------------------- knn (+prep blocks) -------------------------------
__global__ __launch_bounds__(512, 4) void knn_kernel(
    const float* __restrict__ x, const float* __restrict__ w0,
    const float* __restrict__ b0, const float* __restrict__ wstk,
    const float* __restrict__ bstk, const float* __restrict__ g,
    const float* __restrict__ be, const float* __restrict__ bm,
    const float* __restrict__ bv, float* __restrict__ ws) {
  __shared__ float2 xyp[2080];
  __shared__ float2 zsp[2080];
  const int t = threadIdx.x;
  const int bid = blockIdx.x;  // 1056

  if (bid >= 1024) {  // ---- prep path ----
    const int i = (bid - 1024) * 512 + t;  // 16384
    unsigned short* __restrict__ wsh = (unsigned short*)ws;
    const int fo = i >> 7, k = i & 127;
    const float s1 = g[128 + fo] / sqrtf(bv[128 + fo] + EPSF);
    const float s2 = g[256 + fo] / sqrtf(bv[256 + fo] + EPSF);
    unsigned h1, l1, h2, l2;
    split3(wstk[i] * s1, h1, l1);
    split3(wstk[16384 + i] * s2, h2, l2);
    const int dst = ((fo >> 4) * 4 + (k >> 5)) * 512 +
                    (((k >> 3) & 3) * 16 + (fo & 15)) * 8 + (k & 7);
    wsh[OFF16_W1H + dst] = (unsigned short)h1;
    wsh[OFF16_W1L + dst] = (unsigned short)l1;
    wsh[OFF16_W2H + dst] = (unsigned short)h2;
    wsh[OFF16_W2L + dst] = (unsigned short)l2;
    if (bid == 1024 && t < 128) {
      const int f = t;
      const float s0 = g[f] / sqrtf(bv[f] + EPSF);
      const float s1b = g[128 + f] / sqrtf(bv[128 + f] + EPSF);
      const float s2b = g[256 + f] / sqrtf(bv[256 + f] + EPSF);
      ws[OFF_C1 + f] = (bstk[f] - bm[128 + f]) * s1b + be[128 + f];
      ws[OFF_C2 + f] = (bstk[128 + f] - bm[256 + f]) * s2b + be[256 + f];
      float4 wv;
      wv.x = w0[3 * f + 0] * s0;
      wv.y = w0[3 * f + 1] * s0;
      wv.z = w0[3 * f + 2] * s0;
      wv.w = (b0[f] - bm[f]) * s0 + be[f];  // c0
      *((float4*)(ws + OFF_W0F) + f) = wv;
    }
    return;
  }

  const int bb = bid >> 7;
  const int qloc0 = (bid & 127) * 16;
  const float* __restrict__ xb = x + bb * 3 * NN;

  // ---- stage whole batch once ----
#pragma unroll
  for (int k = 0; k < 4; ++k) {
    const int i = t + k * 512;
    const float a0 = xb[i];
    const float a1 = xb[2048 + i];
    const float a2 = xb[4096 + i];
    const float sq = fmaf(a2, a2, fmaf(a1, a1, a0 * a0));
    const int ii = i + (i >> 6);
    xyp[ii] = make_float2(a0, a1);
    zsp[ii] = make_float2(a2, sq);
  }

  const int qi = t >> 5;   // 0..15
  const int sg = t & 31;   // slice
  const int n = qloc0 + qi;
  const int q = bb * NN + n;
  const float qx0 = xb[n], qx1 = xb[2048 + n], qx2 = xb[4096 + n];
  const float sqn = fmaf(qx2, qx2, fmaf(qx1, qx1, qx0 * qx0));
  __syncthreads();

  const float2* __restrict__ xr = xyp + sg * 65;
  const float2* __restrict__ zr = zsp + sg * 65;

  // ---- phase 1: 8 batches of sort-8 + fold; keep ALL distances in VGPRs ----
  float dv[64];
  float k0 = FMAXV, k1 = FMAXV, k2 = FMAXV, k3 = FMAXV,
        k4 = FMAXV, k5 = FMAXV, k6 = FMAXV, k7 = FMAXV;
#pragma unroll
  for (int bt = 0; bt < 8; ++bt) {
    float d0, d1, d2, d3, d4, d5, d6, d7;
#define KD(j, dj)                                                        \
    {                                                                    \
      const float2 cxy = xr[bt * 8 + (j)];                               \
      const float2 czs = zr[bt * 8 + (j)];                               \
      const float inner =                                                \
          fmaf(qx2, czs.x, fmaf(qx1, cxy.y, qx0 * cxy.x));               \
      dj = (sqn - 2.0f * inner) + czs.y;                                 \
    }
    KD(0, d0) KD(1, d1) KD(2, d2) KD(3, d3)
    KD(4, d4) KD(5, d5) KD(6, d6) KD(7, d7)
#undef KD
    dv[bt * 8 + 0] = d0; dv[bt * 8 + 1] = d1;
    dv[bt * 8 + 2] = d2; dv[bt * 8 + 3] = d3;
    dv[bt * 8 + 4] = d4; dv[bt * 8 + 5] = d5;
    dv[bt * 8 + 6] = d6; dv[bt * 8 + 7] = d7;
    SORT8(d0, d1, d2, d3, d4, d5, d6, d7)
    KFOLD8(d0, d1, d2, d3, d4, d5, d6, d7)
  }

  // ---- cross-lane merge: 32 lanes -> exact global 8th-smallest ----
  KMERGE(1) KMERGE(2) KMERGE(4) KMERGE(8) KMERGE(16)
  const float thr = k7;

  // ---- phase 2: register compare-only rescan ----
  unsigned am = 0, bm2 = 0;
#pragma unroll
  for (int mm = 0; mm < 32; ++mm) am |= (dv[mm] <= thr) ? (1u << mm) : 0u;
#pragma unroll
  for (int mm = 0; mm < 32; ++mm)
    bm2 |= (dv[32 + mm] <= thr) ? (1u << mm) : 0u;

  // ---- exclusive scan of per-lane counts over the 32-lane group ----
  const int cnt = __popc(am) + __popc(bm2);
  int inc = cnt, tq;
  tq = __shfl_up(inc, 1, 32); inc += (sg >= 1) ? tq : 0;
  tq = __shfl_up(inc, 2, 32); inc += (sg >= 2) ? tq : 0;
  tq = __shfl_up(inc, 4, 32); inc += (sg >= 4) ? tq : 0;
  tq = __shfl_up(inc, 8, 32); inc += (sg >= 8) ? tq : 0;
  tq = __shfl_up(inc, 16, 32); inc += (sg >= 16) ? tq : 0;
  int pos = inc - cnt;

  // ---- extraction: hits in ascending candidate index (lane-major) ----
  int* __restrict__ idxg = (int*)(ws + OFF_IDX);
  {
    unsigned w = am;
    while (w) {
      const int b = __ffs(w) - 1;
      w &= w - 1;
      if (pos < 8) idxg[q * 8 + pos] = bb * NN + sg * 64 + b;
      ++pos;
    }
    w = bm2;
    while (w) {
      const int b = __ffs(w) - 1;
      w &= w - 1;
      if (pos < 8) idxg[q * 8 + pos] = bb * NN + sg * 64 + 32 + b;
      ++pos;
    }
  }
}

// --------------------------- persistent fused ------------------------------
// R15: 512 blocks x 256 thr (4 waves, wc=w). Block: batch bb=bid&7,
// qseg=bid>>3 (32 queries), 8 chunks of 32 pairs. ONE barrier per chunk.
// LDS 74KB: A0 @0, A1 @16K (each hi8K+lo8K), H0 @32K, H1 @48K,
//           OS(16q) @64K (8KB), W0L @72K (2KB). 2 blocks/CU.
__global__ __launch_bounds__(256, 2) void fused_kernel(
    const float* __restrict__ x, float* __restrict__ ws,
    float* __restrict__ out) {
  extern __shared__ char smem[];
  float* __restrict__ OS = (float*)(smem + 65536);
  float4* __restrict__ W0L = (float4*)(smem + 73728);

  const int* __restrict__ idxg = (const int*)(ws + OFF_IDX);
  const unsigned short* __restrict__ wsu = (const unsigned short*)ws;

  const int t = threadIdx.x;
  const int lane = t & 63, w = t >> 6;
  const int wc = w;
  const int bid = blockIdx.x;
  const int bb = bid & 7, qseg = bid >> 3;
  const int chunk0 = bb * 512 + qseg * 8;
  const float* __restrict__ xb = x + bb * 3 * NN;

  // ---- W0F4 -> LDS, perm(f) = ((f&7)<<4)|(f>>3) ----
  if (t < 128) {
    const float4 wv = *((const float4*)(ws + OFF_W0F) + t);
    W0L[((t & 7) << 4) | (t >> 3)] = wv;
  }

  // ---- W fragments -> registers ----
  short8v w1h[2][4], w1l[2][4], w2h[2][4], w2l[2][4];
#pragma unroll
  for (int ft = 0; ft < 2; ++ft)
#pragma unroll
    for (int ks = 0; ks < 4; ++ks) {
      const int off = ((wc * 2 + ft) * 4 + ks) * 512 + lane * 8;
      w1h[ft][ks] = *(const short8v*)(wsu + OFF16_W1H + off);
      w1l[ft][ks] = *(const short8v*)(wsu + OFF16_W1L + off);
      w2h[ft][ks] = *(const short8v*)(wsu + OFF16_W2H + off);
      w2l[ft][ks] = *(const short8v*)(wsu + OFF16_W2L + off);
    }

  const float c1v0 = (ws + OFF_C1)[wc * 32 + (lane & 15)];
  const float c1v1 = (ws + OFF_C1)[wc * 32 + 16 + (lane & 15)];
  const float c2v0 = (ws + OFF_C2)[wc * 32 + (lane & 15)];
  const float c2v1 = (ws + OFF_C2)[wc * 32 + 16 + (lane & 15)];

  const int row = t >> 3, part8 = t & 7;
  __syncthreads();  // W0L ready

// pack 8 floats into hi/lo int4, write swizzled (lo plane at +8192)
#define PACK_WRITE_A(base, hv, kc)                              \
  {                                                             \
    unsigned hh[8], ll[8];                                      \
    _Pragma("unroll") for (int e = 0; e < 8; ++e)               \
        split3(hv[e], hh[e], ll[e]);                            \
    int4 hp, lp;                                                \
    hp.x = (int)(hh[0] | (hh[1] << 16));                        \
    hp.y = (int)(hh[2] | (hh[3] << 16));                        \
    hp.z = (int)(hh[4] | (hh[5] << 16));                        \
    hp.w = (int)(hh[6] | (hh[7] << 16));                        \
    lp.x = (int)(ll[0] | (ll[1] << 16));                        \
    lp.y = (int)(ll[2] | (ll[3] << 16));                        \
    lp.z = (int)(ll[4] | (ll[5] << 16));                        \
    lp.w = (int)(ll[6] | (ll[7] << 16));                        \
    const int col = (kc) ^ (row & 7);                           \
    *(int4*)((base) + row * 256 + col * 16) = hp;               \
    *(int4*)((base) + 8192 + row * 256 + col * 16) = lp;        \
  }

// compute h1 (16 feats) from rel coords + W0L, pack into A plane
#define STAGE_A(base, R0, R1, R2)                               \
  {                                                             \
    float hv0[8], hv1[8];                                       \
    _Pragma("unroll") for (int e = 0; e < 8; ++e) {             \
      const float4 wa = W0L[e * 16 + part8 * 2];                \
      const float4 wb = W0L[e * 16 + part8 * 2 + 1];            \
      hv0[e] = relu_f(                                          \
          fmaf(wa.z, R2, fmaf(wa.y, R1, fmaf(wa.x, R0, wa.w))));\
      hv1[e] = relu_f(                                          \
          fmaf(wb.z, R2, fmaf(wb.y, R1, fmaf(wb.x, R0, wb.w))));\
    }                                                           \
    PACK_WRITE_A(base, hv0, part8 * 2)                          \
    PACK_WRITE_A(base, hv1, part8 * 2 + 1)                      \
  }

// g1 MFMA on A buffer -> write H buffer (relu(acc+c1) packed u32, swizzled)
#define G1_TO_H(Abase, Hbase)                                           \
  {                                                                     \
    f32x4 acc[2][2];                                                    \
    _Pragma("unroll") for (int pt = 0; pt < 2; ++pt)                    \
        _Pragma("unroll") for (int ft = 0; ft < 2; ++ft)                \
            acc[pt][ft] = (f32x4){0.f, 0.f, 0.f, 0.f};                  \
    __builtin_amdgcn_s_setprio(1);                                      \
    _Pragma("unroll") for (int ks = 0; ks < 4; ++ks) {                  \
      const int kc = ks * 4 + (lane >> 4);                              \
      _Pragma("unroll") for (int pt = 0; pt < 2; ++pt) {                \
        const int arow = pt * 16 + (lane & 15);                         \
        const int col = kc ^ (arow & 7);                                \
        const short8v ah =                                              \
            *(const short8v*)((Abase) + arow * 256 + col * 16);         \
        const short8v al =                                              \
            *(const short8v*)((Abase) + 8192 + arow * 256 + col * 16);  \
        _Pragma("unroll") for (int ft = 0; ft < 2; ++ft) {              \
          acc[pt][ft] = mfma16x16x32bf(al, w1h[ft][ks], acc[pt][ft]);   \
          acc[pt][ft] = mfma16x16x32bf(ah, w1l[ft][ks], acc[pt][ft]);   \
          acc[pt][ft] = mfma16x16x32bf(ah, w1h[ft][ks], acc[pt][ft]);   \
        }                                                               \
      }                                                                 \
    }                                                                   \
    __builtin_amdgcn_s_setprio(0);                                      \
    unsigned* __restrict__ Hp = (unsigned*)(Hbase);                     \
    _Pragma("unroll") for (int pt = 0; pt < 2; ++pt)                    \
        _Pragma("unroll") for (int ft = 0; ft < 2; ++ft) {              \
      const int fo = wc * 32 + ft * 16 + (lane & 15);                   \
      const int cc = fo >> 2;                                           \
      const float cb = ft ? c1v1 : c1v0;                                \
      _Pragma("unroll") for (int reg = 0; reg < 4; ++reg) {             \
        const int p = pt * 16 + (lane >> 4) * 4 + reg;                  \
        const float vv = relu_f(acc[pt][ft][reg] + cb);                 \
        unsigned hh, ll;                                                \
        split3(vv, hh, ll);                                             \
        Hp[p * 128 + ((cc ^ (p & 7)) << 2) + (fo & 3)] = (hh << 16) | ll; \
      }                                                                 \
    }                                                                   \
  }

// g2 MFMA on H buffer -> relu+max -> OS rows (CH&3)*4
#define G2_TO_OS(Hbase, CH)                                             \
  {                                                                     \
    const unsigned* __restrict__ Hp = (const unsigned*)(Hbase);         \
    f32x4 acc2[2][2];                                                   \
    _Pragma("unroll") for (int pt = 0; pt < 2; ++pt)                    \
        _Pragma("unroll") for (int ft = 0; ft < 2; ++ft)                \
            acc2[pt][ft] = (f32x4){0.f, 0.f, 0.f, 0.f};                 \
    __builtin_amdgcn_s_setprio(1);                                      \
    _Pragma("unroll") for (int ks = 0; ks < 4; ++ks) {                  \
      const int cc0 = ks * 8 + (lane >> 4) * 2;                         \
      _Pragma("unroll") for (int pt = 0; pt < 2; ++pt) {                \
        const int p = pt * 16 + (lane & 15);                            \
        const int4 u0 = *(const int4*)&Hp[p * 128 + ((cc0 ^ (p & 7)) << 2)]; \
        const int4 u1 =                                                 \
            *(const int4*)&Hp[p * 128 + (((cc0 + 1) ^ (p & 7)) << 2)];  \
        const unsigned uu[8] = {(unsigned)u0.x, (unsigned)u0.y,         \
                                (unsigned)u0.z, (unsigned)u0.w,         \
                                (unsigned)u1.x, (unsigned)u1.y,         \
                                (unsigned)u1.z, (unsigned)u1.w};        \
        short8v ah, al;                                                 \
        _Pragma("unroll") for (int e = 0; e < 8; ++e) {                 \
          ah[e] = (short)(uu[e] >> 16);                                 \
          al[e] = (short)(uu[e] & 0xFFFFu);                             \
        }                                                               \
        _Pragma("unroll") for (int ft = 0; ft < 2; ++ft) {              \
          acc2[pt][ft] = mfma16x16x32bf(al, w2h[ft][ks], acc2[pt][ft]); \
          acc2[pt][ft] = mfma16x16x32bf(ah, w2l[ft][ks], acc2[pt][ft]); \
          acc2[pt][ft] = mfma16x16x32bf(ah, w2h[ft][ks], acc2[pt][ft]); \
        }                                                               \
      }                                                                 \
    }                                                                   \
    __builtin_amdgcn_s_setprio(0);                                      \
    const int g = lane >> 4;                                            \
    _Pragma("unroll") for (int pt = 0; pt < 2; ++pt)                    \
        _Pragma("unroll") for (int ft = 0; ft < 2; ++ft) {              \
      const int fo = wc * 32 + ft * 16 + (lane & 15);                   \
      const float cb = ft ? c2v1 : c2v0;                                \
      const float v0 = relu_f(acc2[pt][ft][0] + cb);                    \
      const float v1 = relu_f(acc2[pt][ft][1] + cb);                    \
      const float v2 = relu_f(acc2[pt][ft][2] + cb);                    \
      const float v3 = relu_f(acc2[pt][ft][3] + cb);                    \
      float m = fmaxf(fmaxf(v0, v1), fmaxf(v2, v3));                    \
      m = fmaxf(m, __shfl_xor(m, 16, 64));                              \
      if ((g & 1) == 0) {                                               \
        const int qloc = pt * 2 + (g >> 1);                             \
        OS[(((CH) & 3) * 4 + qloc) * 128 + fo] = m;                     \
      }                                                                 \
    }                                                                   \
  }

// write OS half h (queries qseg*32 + h*16 .. +16)
#define OS_FLUSH(h)                                                     \
  {                                                                     \
    const int f = t >> 1, sh = t & 1;                                   \
    float* __restrict__ op = out + (long)(bb * 128 + f) * 2048 +        \
                             qseg * 32 + (h) * 16 + sh * 8;             \
    float4 o1, o2;                                                      \
    o1.x = OS[(sh * 8 + 0) * 128 + f];                                  \
    o1.y = OS[(sh * 8 + 1) * 128 + f];                                  \
    o1.z = OS[(sh * 8 + 2) * 128 + f];                                  \
    o1.w = OS[(sh * 8 + 3) * 128 + f];                                  \
    o2.x = OS[(sh * 8 + 4) * 128 + f];                                  \
    o2.y = OS[(sh * 8 + 5) * 128 + f];                                  \
    o2.z = OS[(sh * 8 + 6) * 128 + f];                                  \
    o2.w = OS[(sh * 8 + 7) * 128 + f];                                  \
    *(float4*)op = o1;                                                  \
    *(float4*)(op + 4) = o2;                                            \
  }

#define LOAD_R(CH, MG, R0, R1, R2)                     \
  {                                                    \
    const int mloc = (MG) & 2047;                      \
    const int nloc = ((((CH) * 32 + row)) >> 3) & 2047;\
    R0 = xb[mloc] - xb[nloc];                          \
    R1 = xb[2048 + mloc] - xb[2048 + nloc];            \
    R2 = xb[4096 + mloc] - xb[4096 + nloc];            \
  }

  // ---- prologue ----
  {
    const int mg0 = idxg[(chunk0 + 0) * 32 + row];
    const int mg1 = idxg[(chunk0 + 1) * 32 + row];
    float r0, r1, r2;
    LOAD_R(chunk0 + 0, mg0, r0, r1, r2)
    STAGE_A(smem, r0, r1, r2)
    __syncthreads();  // A0 ready
    G1_TO_H(smem, smem + 32768)  // chunk0: A0 -> H0
    LOAD_R(chunk0 + 1, mg1, r0, r1, r2)
    STAGE_A(smem + 16384, r0, r1, r2)  // A1 <- chunk1
    __syncthreads();  // H0, A1 ready
  }

  // ---- main loop: one barrier per chunk ----
#pragma unroll 1
  for (int j = 0; j < 8; ++j) {
    // prefetch idx for chunk j+2 (covered by the 96-MFMA cluster below)
    int mg2 = 0;
    if (j < 6) mg2 = idxg[(chunk0 + j + 2) * 32 + row];

    G2_TO_OS(smem + 32768 + (j & 1) * 16384, j)  // g2 chunk j from H[j&1]

    if (j < 7) {
      G1_TO_H(smem + ((j + 1) & 1) * 16384,
              smem + 32768 + ((j + 1) & 1) * 16384)  // chunk j+1
      if (j < 6) {
        float r0, r1, r2;
        LOAD_R(chunk0 + j + 2, mg2, r0, r1, r2)
        STAGE_A(smem + (j & 1) * 16384, r0, r1, r2)  // A[j&1] <- chunk j+2
      }
    }
    __syncthreads();
    if (j == 3) {
      OS_FLUSH(0)
      __syncthreads();
    }
  }
  OS_FLUSH(1)
}

// ------------------------------- launch ------------------------------------
extern "C" void kernel_launch(void* const* d_in, const int* in_sizes, int n_in,
                              void* d_out, int out_size, void* d_ws,
                              size_t ws_size, hipStream_t stream) {
  (void)in_sizes; (void)n_in; (void)out_size; (void)ws_size;
  const float* x = (const float*)d_in[0];
  const float* w0 = (const float*)d_in[1];
  const float* b0 = (const float*)d_in[2];
  const float* wst = (const float*)d_in[3];
  const float* bst = (const float*)d_in[4];
  const float* g = (const float*)d_in[5];
  const float* be = (const float*)d_in[6];
  const float* bm = (const float*)d_in[7];
  const float* bv = (const float*)d_in[8];
  float* out = (float*)d_out;
  float* ws = (float*)d_ws;

  hipFuncSetAttribute((const void*)fused_kernel,
                      hipFuncAttributeMaxDynamicSharedMemorySize, 75776);

  knn_kernel<<<1056, 512, 0, stream>>>(x, w0, b0, wst, bst, g, be, bm, bv, ws);
  fused_kernel<<<512, 256, 75776, stream>>>(x, ws, out);
}